// Round 1
// baseline (2675.093 us; speedup 1.0000x reference)
//
#include <hip/hip_runtime.h>
#include <hip/hip_bf16.h>
#include <stdint.h>

// Problem constants (fixed by the reference)
#define NB 16
#define NN 4096
#define NCF 64
#define NS 1024
#define NK 32
#define NPTS (NB*NS*NK)   // 524288
#define CIN 67
#define EPSV 1e-5f

// rn intrinsics: block FMA contraction so FPS/kNN distances bit-match numpy
static __device__ __forceinline__ float fmul(float a, float b){ return __fmul_rn(a,b); }
static __device__ __forceinline__ float fadd(float a, float b){ return __fadd_rn(a,b); }
static __device__ __forceinline__ float fsub(float a, float b){ return __fsub_rn(a,b); }

static __device__ __forceinline__ unsigned short f2b(float f){
  unsigned u = __float_as_uint(f);
  return (unsigned short)((u + 0x7FFFu + ((u>>16)&1u)) >> 16);  // RNE bf16
}

// ---------------------------------------------------------------------------
// prep: transpose points (B,CF,N)->(B,N,CF) and compute sq_xyz with rn ops
// ---------------------------------------------------------------------------
__global__ __launch_bounds__(256) void prep_kernel(const float* __restrict__ pts,
    const float* __restrict__ xyz, float* __restrict__ ptsT, float* __restrict__ sqx){
  int blk = blockIdx.x;            // 256 blocks = 16 b * 16 chunks
  int b = blk >> 4;
  int n = ((blk & 15) << 8) + threadIdx.x;
  const float* src = pts + (size_t)b*NCF*NN + n;
  float v[NCF];
  #pragma unroll
  for (int c=0;c<NCF;c++) v[c] = src[(size_t)c*NN];
  float4* dst = (float4*)(ptsT + ((size_t)b*NN + n)*NCF);
  #pragma unroll
  for (int j=0;j<16;j++) dst[j] = make_float4(v[4*j],v[4*j+1],v[4*j+2],v[4*j+3]);
  const float* xp = xyz + ((size_t)b*NN + n)*3;
  float x=xp[0], y=xp[1], z=xp[2];
  sqx[(size_t)b*NN+n] = fadd(fadd(fmul(x,x),fmul(y,y)),fmul(z,z));
}

// ---------------------------------------------------------------------------
// FPS: one block per batch, 512 threads, 8 pts/thread in registers.
// 3-slot rotating LDS atomicMax keeps it to ONE barrier per step.
// Key = (f32 bits << 32) | (0xFFFFFFFF - idx): argmax value, tie -> lowest idx
// (matches np.argmax first-occurrence semantics).
// ---------------------------------------------------------------------------
#define FT 512
#define FPP (NN/FT)
__global__ __launch_bounds__(FT) void fps_kernel(const float* __restrict__ xyz,
    int* __restrict__ fidx, float* __restrict__ newxyz){
  int b = blockIdx.x;
  __shared__ float sx[NN], sy[NN], sz[NN];
  __shared__ unsigned long long slot[3];
  const int tid = threadIdx.x;
  for (int i = tid; i < NN; i += FT){
    const float* p = xyz + ((size_t)b*NN + i)*3;
    sx[i]=p[0]; sy[i]=p[1]; sz[i]=p[2];
  }
  if (tid < 3) slot[tid]=0ULL;
  __syncthreads();
  float px[FPP],py[FPP],pz[FPP],dist[FPP];
  #pragma unroll
  for (int j=0;j<FPP;j++){ int n=tid+FT*j; px[j]=sx[n]; py[j]=sy[n]; pz[j]=sz[n]; dist[j]=1e10f; }
  int far = 0;
  float cx=sx[0], cy=sy[0], cz=sz[0];
  for (int s=0;s<NS;s++){
    if (tid==0){
      fidx[b*NS+s] = far;
      float* o = newxyz + ((size_t)b*NS+s)*3;
      o[0]=cx; o[1]=cy; o[2]=cz;
      slot[(s+1)%3] = 0ULL;   // safe: that slot's readers finished before barrier(s-1)
    }
    float bv = -1.0f; int bi = 0;
    #pragma unroll
    for (int j=0;j<FPP;j++){
      float dx=fsub(px[j],cx), dy=fsub(py[j],cy), dz=fsub(pz[j],cz);
      float d = fadd(fadd(fmul(dx,dx),fmul(dy,dy)),fmul(dz,dz));
      d = fminf(dist[j], d); dist[j] = d;
      int n = tid + FT*j;
      if (d > bv || (d == bv && n < bi)) { bv = d; bi = n; }
    }
    #pragma unroll
    for (int off=32; off>=1; off>>=1){
      float ov = __shfl_xor(bv, off);
      int  oi = __shfl_xor(bi, off);
      if (ov > bv || (ov == bv && oi < bi)) { bv = ov; bi = oi; }
    }
    if ((tid & 63) == 0){
      unsigned long long key = ((unsigned long long)__float_as_uint(bv) << 32)
                             | (unsigned long long)(0xFFFFFFFFu - (unsigned)bi);
      atomicMax(&slot[s%3], key);
    }
    __syncthreads();
    unsigned long long kk = slot[s%3];
    far = (int)(0xFFFFFFFFu - (unsigned)(kk & 0xFFFFFFFFULL));
    cx = sx[far]; cy = sy[far]; cz = sz[far];
  }
}

__global__ __launch_bounds__(256) void dcen_kernel(const float* __restrict__ density,
    const int* __restrict__ fidx, float* __restrict__ dcen){
  int i = blockIdx.x*256 + threadIdx.x;   // 16384
  int b = i >> 10;
  dcen[i] = density[(size_t)b*NN + fidx[i]];
}

__global__ __launch_bounds__(256) void dstats_kernel(const float* __restrict__ dcen,
    float* __restrict__ dstat){
  float s=0.f, q=0.f;
  for (int i=threadIdx.x; i<NB*NS; i+=256){ float v=dcen[i]; s+=v; q+=v*v; }
  __shared__ float ls[256], lq[256];
  ls[threadIdx.x]=s; lq[threadIdx.x]=q;
  __syncthreads();
  for (int off=128; off>0; off>>=1){
    if (threadIdx.x<off){ ls[threadIdx.x]+=ls[threadIdx.x+off]; lq[threadIdx.x]+=lq[threadIdx.x+off]; }
    __syncthreads();
  }
  if (threadIdx.x==0){
    float m = ls[0]/(float)(NB*NS);
    dstat[0]=m; dstat[1]=lq[0]/(float)(NB*NS) - m*m;
  }
}

// ---------------------------------------------------------------------------
// kNN: one wave per center; wave-held top-32 (keys in lanes 0..31),
// serialized ballot insertion. Key = sortable(d) << 32 | n  (tie -> lowest n).
// Neighbor ORDER is irrelevant downstream (perm-invariant MLP+max), only set.
// ---------------------------------------------------------------------------
__global__ __launch_bounds__(256) void knn_kernel(const float* __restrict__ xyz,
    const float* __restrict__ sqx, const float* __restrict__ newxyz,
    int* __restrict__ kidx){
  const int lane = threadIdx.x & 63;
  const int g = blockIdx.x*4 + (threadIdx.x >> 6);
  const int b = g >> 10;
  const float* cp = newxyz + (size_t)g*3;
  const float cx=cp[0], cy=cp[1], cz=cp[2];
  const float sqc = fadd(fadd(fmul(cx,cx),fmul(cy,cy)),fmul(cz,cz));
  const float* xb  = xyz + (size_t)b*NN*3;
  const float* sqb = sqx + (size_t)b*NN;
  unsigned long long kept  = ~0ULL;
  unsigned long long worst = ~0ULL;
  int worstLane = 0;
  for (int n0=0; n0<NN; n0+=64){
    const int n = n0 + lane;
    const float* xp = xb + (size_t)n*3;
    float x=xp[0], y=xp[1], z=xp[2];
    float dot = fadd(fadd(fmul(cx,x),fmul(cy,y)),fmul(cz,z));
    float d = fsub(fadd(sqc, sqb[n]), fmul(2.0f,dot));
    unsigned u = __float_as_uint(d);
    u = (u & 0x80000000u) ? ~u : (u | 0x80000000u);   // total order incl. negatives
    unsigned long long ck = ((unsigned long long)u << 32) | (unsigned)n;
    unsigned long long mask = __ballot(ck < worst);
    while (mask){
      const int l = __ffsll((unsigned long long)mask) - 1;
      mask &= mask - 1;
      const unsigned long long k = __shfl(ck, l);
      if (k < worst){                       // uniform: worst/k uniform across wave
        if (lane == worstLane) kept = k;
        unsigned long long wv = (lane < 32) ? kept : 0ULL;
        int wl = lane;
        #pragma unroll
        for (int off=32; off>=1; off>>=1){
          unsigned long long ov = __shfl_xor(wv, off);
          int ol = __shfl_xor(wl, off);
          if (ov > wv || (ov == wv && ol < wl)) { wv = ov; wl = ol; }
        }
        worst = wv; worstLane = wl;
      }
    }
  }
  if (lane < 32) kidx[(size_t)g*NK + lane] = (int)(kept & 0xFFFFFFFFULL);
}

// ---------------------------------------------------------------------------
// conv kernels: block=256, 2pts x 16outs per thread, inputs+weights in LDS.
// Each writes raw pre-BN z (bf16) + per-block per-channel (sum,sumsq) partials.
// ---------------------------------------------------------------------------
__global__ __launch_bounds__(256) void conv1_kernel(const float* __restrict__ xyz,
    const float* __restrict__ ptsT, const float* __restrict__ newxyz,
    const int* __restrict__ kidx, const float* __restrict__ w0,
    const float* __restrict__ b0, unsigned short* __restrict__ z1,
    float* __restrict__ partial){
  __shared__ float si[CIN][128];
  __shared__ float sw[CIN][64];
  __shared__ float sbias[64];
  const int tid = threadIdx.x;
  for (int i = tid; i < CIN*64; i += 256){
    int o = i / CIN, c = i - o*CIN;
    sw[c][o] = w0[i];
  }
  if (tid < 64) sbias[tid] = b0[tid];
  const int p0 = blockIdx.x * 128;
  if (tid < 128){
    const int p = p0 + tid;
    const int g = p >> 5;
    const int b = g >> 10;
    const int n = kidx[p];
    const float* xp = xyz + ((size_t)b*NN + n)*3;
    const float* cp = newxyz + (size_t)g*3;
    si[0][tid] = xp[0]-cp[0];
    si[1][tid] = xp[1]-cp[1];
    si[2][tid] = xp[2]-cp[2];
    const float4* pr = (const float4*)(ptsT + ((size_t)b*NN + n)*NCF);
    #pragma unroll
    for (int j=0;j<16;j++){
      float4 v = pr[j];
      si[3+4*j][tid]=v.x; si[4+4*j][tid]=v.y; si[5+4*j][tid]=v.z; si[6+4*j][tid]=v.w;
    }
  }
  __syncthreads();
  const int og = tid >> 6;     // wave id, 16 outputs
  const int pg = tid & 63;     // 2 points
  float acc0[16], acc1[16];
  #pragma unroll
  for (int j=0;j<16;j++){ float bv = sbias[og*16+j]; acc0[j]=bv; acc1[j]=bv; }
  for (int c=0;c<CIN;c++){
    float2 a = *(const float2*)&si[c][2*pg];
    const float4* wr = (const float4*)&sw[c][og*16];
    #pragma unroll
    for (int q=0;q<4;q++){
      float4 w = wr[q];
      acc0[4*q+0]+=a.x*w.x; acc0[4*q+1]+=a.x*w.y; acc0[4*q+2]+=a.x*w.z; acc0[4*q+3]+=a.x*w.w;
      acc1[4*q+0]+=a.y*w.x; acc1[4*q+1]+=a.y*w.y; acc1[4*q+2]+=a.y*w.z; acc1[4*q+3]+=a.y*w.w;
    }
  }
  unsigned v[8];
  #pragma unroll
  for (int j=0;j<8;j++) v[j] = (unsigned)f2b(acc0[2*j]) | ((unsigned)f2b(acc0[2*j+1])<<16);
  uint4* d0 = (uint4*)(z1 + (size_t)(p0+2*pg)*64 + og*16);
  d0[0]=make_uint4(v[0],v[1],v[2],v[3]); d0[1]=make_uint4(v[4],v[5],v[6],v[7]);
  #pragma unroll
  for (int j=0;j<8;j++) v[j] = (unsigned)f2b(acc1[2*j]) | ((unsigned)f2b(acc1[2*j+1])<<16);
  uint4* d1 = (uint4*)(z1 + (size_t)(p0+2*pg+1)*64 + og*16);
  d1[0]=make_uint4(v[0],v[1],v[2],v[3]); d1[1]=make_uint4(v[4],v[5],v[6],v[7]);
  #pragma unroll
  for (int j=0;j<16;j++){
    float s = acc0[j]+acc1[j];
    float q = acc0[j]*acc0[j] + acc1[j]*acc1[j];
    #pragma unroll
    for (int off=32; off>=1; off>>=1){ s += __shfl_xor(s,off); q += __shfl_xor(q,off); }
    if (pg==0){
      partial[(size_t)blockIdx.x*128 + og*16 + j] = s;
      partial[(size_t)blockIdx.x*128 + 64 + og*16 + j] = q;
    }
  }
}

__global__ __launch_bounds__(256) void conv2_kernel(const unsigned short* __restrict__ z1,
    const float* __restrict__ w1, const float* __restrict__ b1,
    const float* __restrict__ scale1, const float* __restrict__ shift1,
    unsigned short* __restrict__ z2, float* __restrict__ partial){
  __shared__ float si[64][128];
  __shared__ float sw[64][64];
  __shared__ float sbias[64];
  const int tid = threadIdx.x;
  for (int i = tid; i < 64*64; i += 256){
    int o = i >> 6, c = i & 63;
    sw[c][o] = w1[i];
  }
  if (tid < 64) sbias[tid] = b1[tid];
  const int p0 = blockIdx.x * 128;
  if (tid < 128){
    const uint4* zr = (const uint4*)(z1 + (size_t)(p0 + tid)*64);
    #pragma unroll
    for (int j=0;j<8;j++){
      uint4 vv = zr[j];
      unsigned a[4] = {vv.x, vv.y, vv.z, vv.w};
      #pragma unroll
      for (int t=0;t<4;t++){
        int c = j*8 + t*2;
        float lo = __uint_as_float(a[t] << 16);
        float hi = __uint_as_float(a[t] & 0xFFFF0000u);
        si[c][tid]   = fmaxf(lo*scale1[c]   + shift1[c],   0.0f);
        si[c+1][tid] = fmaxf(hi*scale1[c+1] + shift1[c+1], 0.0f);
      }
    }
  }
  __syncthreads();
  const int og = tid >> 6;
  const int pg = tid & 63;
  float acc0[16], acc1[16];
  #pragma unroll
  for (int j=0;j<16;j++){ float bv = sbias[og*16+j]; acc0[j]=bv; acc1[j]=bv; }
  for (int c=0;c<64;c++){
    float2 a = *(const float2*)&si[c][2*pg];
    const float4* wr = (const float4*)&sw[c][og*16];
    #pragma unroll
    for (int q=0;q<4;q++){
      float4 w = wr[q];
      acc0[4*q+0]+=a.x*w.x; acc0[4*q+1]+=a.x*w.y; acc0[4*q+2]+=a.x*w.z; acc0[4*q+3]+=a.x*w.w;
      acc1[4*q+0]+=a.y*w.x; acc1[4*q+1]+=a.y*w.y; acc1[4*q+2]+=a.y*w.z; acc1[4*q+3]+=a.y*w.w;
    }
  }
  unsigned v[8];
  #pragma unroll
  for (int j=0;j<8;j++) v[j] = (unsigned)f2b(acc0[2*j]) | ((unsigned)f2b(acc0[2*j+1])<<16);
  uint4* d0 = (uint4*)(z2 + (size_t)(p0+2*pg)*64 + og*16);
  d0[0]=make_uint4(v[0],v[1],v[2],v[3]); d0[1]=make_uint4(v[4],v[5],v[6],v[7]);
  #pragma unroll
  for (int j=0;j<8;j++) v[j] = (unsigned)f2b(acc1[2*j]) | ((unsigned)f2b(acc1[2*j+1])<<16);
  uint4* d1 = (uint4*)(z2 + (size_t)(p0+2*pg+1)*64 + og*16);
  d1[0]=make_uint4(v[0],v[1],v[2],v[3]); d1[1]=make_uint4(v[4],v[5],v[6],v[7]);
  #pragma unroll
  for (int j=0;j<16;j++){
    float s = acc0[j]+acc1[j];
    float q = acc0[j]*acc0[j] + acc1[j]*acc1[j];
    #pragma unroll
    for (int off=32; off>=1; off>>=1){ s += __shfl_xor(s,off); q += __shfl_xor(q,off); }
    if (pg==0){
      partial[(size_t)blockIdx.x*128 + og*16 + j] = s;
      partial[(size_t)blockIdx.x*128 + 64 + og*16 + j] = q;
    }
  }
}

// conv3: 64 pts/block (2 centers), 8 out-groups; fuses max over k (valid pre-BN
// because BN3 scale = g3*rsqrt(var+eps) > 0 with g3=1 and density weight >= 0).
__global__ __launch_bounds__(256) void conv3_kernel(const unsigned short* __restrict__ z2,
    const float* __restrict__ w2, const float* __restrict__ b2,
    const float* __restrict__ scale2, const float* __restrict__ shift2,
    float* __restrict__ m3, float* __restrict__ partial){
  __shared__ float si[64][64];
  __shared__ float sw[64][128];
  __shared__ float sbias[128];
  const int tid = threadIdx.x;
  for (int i = tid; i < 64*128; i += 256){
    int o = i >> 6, c = i & 63;
    sw[c][o] = w2[i];
  }
  if (tid < 128) sbias[tid] = b2[tid];
  const int p0 = blockIdx.x * 64;
  if (tid < 64){
    const uint4* zr = (const uint4*)(z2 + (size_t)(p0 + tid)*64);
    #pragma unroll
    for (int j=0;j<8;j++){
      uint4 vv = zr[j];
      unsigned a[4]={vv.x,vv.y,vv.z,vv.w};
      #pragma unroll
      for (int t=0;t<4;t++){
        int c = j*8+t*2;
        float lo=__uint_as_float(a[t]<<16), hi=__uint_as_float(a[t]&0xFFFF0000u);
        si[c][tid]   = fmaxf(lo*scale2[c]+shift2[c],0.f);
        si[c+1][tid] = fmaxf(hi*scale2[c+1]+shift2[c+1],0.f);
      }
    }
  }
  __syncthreads();
  const int og = tid >> 5;    // 0..7 -> outputs og*16..+15
  const int pg = tid & 31;    // 2 points
  float acc0[16], acc1[16];
  #pragma unroll
  for (int j=0;j<16;j++){ float bv=sbias[og*16+j]; acc0[j]=bv; acc1[j]=bv; }
  for (int c=0;c<64;c++){
    float2 a = *(const float2*)&si[c][2*pg];
    const float4* wr = (const float4*)&sw[c][og*16];
    #pragma unroll
    for (int q=0;q<4;q++){
      float4 w=wr[q];
      acc0[4*q+0]+=a.x*w.x; acc0[4*q+1]+=a.x*w.y; acc0[4*q+2]+=a.x*w.z; acc0[4*q+3]+=a.x*w.w;
      acc1[4*q+0]+=a.y*w.x; acc1[4*q+1]+=a.y*w.y; acc1[4*q+2]+=a.y*w.z; acc1[4*q+3]+=a.y*w.w;
    }
  }
  float mx[16];
  #pragma unroll
  for (int j=0;j<16;j++){
    float m = fmaxf(acc0[j], acc1[j]);
    #pragma unroll
    for (int off=8; off>=1; off>>=1) m = fmaxf(m, __shfl_xor(m, off));
    mx[j]=m;
  }
  if ((pg & 15)==0){
    const int center = (p0 + 2*pg) >> 5;
    float* mp = m3 + (size_t)center*128 + og*16;
    #pragma unroll
    for (int j=0;j<16;j++) mp[j]=mx[j];
  }
  #pragma unroll
  for (int j=0;j<16;j++){
    float s=acc0[j]+acc1[j];
    float q=acc0[j]*acc0[j]+acc1[j]*acc1[j];
    #pragma unroll
    for (int off=16; off>=1; off>>=1){ s+=__shfl_xor(s,off); q+=__shfl_xor(q,off); }
    if (pg==0){
      partial[(size_t)blockIdx.x*256 + og*16 + j] = s;
      partial[(size_t)blockIdx.x*256 + 128 + og*16 + j] = q;
    }
  }
}

// reduce per-block partials -> BN scale/shift per channel (one block per channel)
__global__ __launch_bounds__(256) void mkbn_kernel(const float* __restrict__ partial,
    int nrows, int stride, const float* __restrict__ g, const float* __restrict__ be,
    float* __restrict__ scale, float* __restrict__ shift, float inv_count){
  const int c = blockIdx.x;
  const int C = gridDim.x;
  float s=0.f, q=0.f;
  for (int r=threadIdx.x; r<nrows; r+=256){
    s += partial[(size_t)r*stride + c];
    q += partial[(size_t)r*stride + C + c];
  }
  __shared__ float ls[256], lq[256];
  ls[threadIdx.x]=s; lq[threadIdx.x]=q;
  __syncthreads();
  for (int off=128; off>0; off>>=1){
    if (threadIdx.x < off){ ls[threadIdx.x]+=ls[threadIdx.x+off]; lq[threadIdx.x]+=lq[threadIdx.x+off]; }
    __syncthreads();
  }
  if (threadIdx.x==0){
    float mean = ls[0]*inv_count;
    float var  = lq[0]*inv_count - mean*mean;
    float sc = g[c]*rsqrtf(var + EPSV);
    scale[c]=sc; shift[c]=be[c]-mean*sc;
  }
}

// out[b,ch,s] = relu(scale3*maxz + shift3) * relu(bn_d(wd*dcen+bd))
__global__ __launch_bounds__(256) void final_kernel(const float* __restrict__ m3,
    const float* __restrict__ dcen, const float* __restrict__ scale3,
    const float* __restrict__ shift3, const float* __restrict__ wd,
    const float* __restrict__ bd, const float* __restrict__ gd,
    const float* __restrict__ bed, const float* __restrict__ dstat,
    float* __restrict__ out){
  size_t i = (size_t)blockIdx.x*256 + threadIdx.x;   // 2,097,152 = b*2^17 + ch*2^10 + s
  int s  = (int)(i & 1023);
  int ch = (int)((i >> 10) & 127);
  int b  = (int)(i >> 17);
  float mean_d = dstat[0], var_d = dstat[1];
  float w = wd[ch];
  float meanp = w*mean_d + bd[ch];
  float varp  = w*w*var_d;          // var of affine(dcen): exact algebraic identity
  float dsc = gd[ch]*rsqrtf(varp + EPSV);
  float dsh = bed[ch] - meanp*dsc;
  float pre = w*dcen[b*NS+s] + bd[ch];
  float dw  = fmaxf(dsc*pre + dsh, 0.0f);
  float z   = m3[((size_t)(b*NS+s))*128 + ch];
  float x   = fmaxf(scale3[ch]*z + shift3[ch], 0.0f);
  out[i] = x*dw;
}

// ---------------------------------------------------------------------------
extern "C" void kernel_launch(void* const* d_in, const int* in_sizes, int n_in,
                              void* d_out, int out_size, void* d_ws, size_t ws_size,
                              hipStream_t stream){
  const float* xyz     = (const float*)d_in[0];
  const float* points  = (const float*)d_in[1];
  const float* density = (const float*)d_in[2];
  const float* w0 = (const float*)d_in[3];
  const float* b0 = (const float*)d_in[4];
  const float* g0 = (const float*)d_in[5];
  const float* be0= (const float*)d_in[6];
  const float* w1 = (const float*)d_in[7];
  const float* b1 = (const float*)d_in[8];
  const float* g1 = (const float*)d_in[9];
  const float* be1= (const float*)d_in[10];
  const float* w2 = (const float*)d_in[11];
  const float* b2 = (const float*)d_in[12];
  const float* g2 = (const float*)d_in[13];
  const float* be2= (const float*)d_in[14];
  const float* wd = (const float*)d_in[15];
  const float* bd = (const float*)d_in[16];
  const float* gd = (const float*)d_in[17];
  const float* bed= (const float*)d_in[18];

  float* out = (float*)d_out;
  float* newxyz = out;                 // (B,S,3) = output 0
  float* out1   = out + (size_t)NB*NS*3;

  // workspace layout (~174 MB total)
  float* ptsT = (float*)d_ws;                            // 4,194,304 f
  float* sqx  = ptsT + (size_t)NB*NN*NCF;                // 65,536 f
  int*   fidx = (int*)(sqx + (size_t)NB*NN);             // 16,384 i
  float* dcen = (float*)(fidx + NB*NS);                  // 16,384 f
  int*   kidx = (int*)(dcen + NB*NS);                    // 524,288 i
  unsigned short* z1 = (unsigned short*)(kidx + NPTS);   // 33,554,432 us
  unsigned short* z2 = z1 + (size_t)NPTS*64;             // 33,554,432 us
  float* m3   = (float*)(z2 + (size_t)NPTS*64);          // 2,097,152 f
  float* p1   = m3 + (size_t)NB*NS*128;                  // 4096*128 f
  float* p2   = p1 + 4096*128;                           // 4096*128 f
  float* p3   = p2 + 4096*128;                           // 8192*256 f
  float* bnp  = p3 + 8192*256;                           // 512 f (scale/shift x3)
  float* dstat= bnp + 512;                               // 2 f

  hipLaunchKernelGGL(prep_kernel,  dim3(256),  dim3(256), 0, stream, points, xyz, ptsT, sqx);
  hipLaunchKernelGGL(fps_kernel,   dim3(NB),   dim3(FT),  0, stream, xyz, fidx, newxyz);
  hipLaunchKernelGGL(dcen_kernel,  dim3(64),   dim3(256), 0, stream, density, fidx, dcen);
  hipLaunchKernelGGL(dstats_kernel,dim3(1),    dim3(256), 0, stream, dcen, dstat);
  hipLaunchKernelGGL(knn_kernel,   dim3(4096), dim3(256), 0, stream, xyz, sqx, newxyz, kidx);
  hipLaunchKernelGGL(conv1_kernel, dim3(4096), dim3(256), 0, stream, xyz, ptsT, newxyz, kidx, w0, b0, z1, p1);
  hipLaunchKernelGGL(mkbn_kernel,  dim3(64),   dim3(256), 0, stream, p1, 4096, 128, g0, be0, bnp+0,   bnp+64,  1.0f/(float)NPTS);
  hipLaunchKernelGGL(conv2_kernel, dim3(4096), dim3(256), 0, stream, z1, w1, b1, bnp+0, bnp+64, z2, p2);
  hipLaunchKernelGGL(mkbn_kernel,  dim3(64),   dim3(256), 0, stream, p2, 4096, 128, g1, be1, bnp+128, bnp+192, 1.0f/(float)NPTS);
  hipLaunchKernelGGL(conv3_kernel, dim3(8192), dim3(256), 0, stream, z2, w2, b2, bnp+128, bnp+192, m3, p3);
  hipLaunchKernelGGL(mkbn_kernel,  dim3(128),  dim3(256), 0, stream, p3, 8192, 256, g2, be2, bnp+256, bnp+384, 1.0f/(float)NPTS);
  hipLaunchKernelGGL(final_kernel, dim3(8192), dim3(256), 0, stream, m3, dcen, bnp+256, bnp+384, wd, bd, gd, bed, dstat, out1);
}

// Round 2
// 1964.881 us; speedup vs baseline: 1.3615x; 1.3615x over previous
//
#include <hip/hip_runtime.h>
#include <hip/hip_bf16.h>
#include <stdint.h>

// Problem constants (fixed by the reference)
#define NB 16
#define NN 4096
#define NCF 64
#define NS 1024
#define NK 32
#define NPTS (NB*NS*NK)   // 524288
#define CIN 67
#define EPSV 1e-5f

// rn intrinsics: block FMA contraction so FPS/kNN distances bit-match numpy
static __device__ __forceinline__ float fmul(float a, float b){ return __fmul_rn(a,b); }
static __device__ __forceinline__ float fadd(float a, float b){ return __fadd_rn(a,b); }
static __device__ __forceinline__ float fsub(float a, float b){ return __fsub_rn(a,b); }

typedef float f2 __attribute__((ext_vector_type(2)));
// Packed f32 ops (VOP3P, CDNA2+): per-element rn add/mul, identical semantics
// to scalar v_add_f32/v_mul_f32 — safe for the exact-index FPS recipe.
#define PK_ADD(d,a,b) asm("v_pk_add_f32 %0, %1, %2" : "=v"(d) : "v"(a), "v"(b))
#define PK_MUL(d,a,b) asm("v_pk_mul_f32 %0, %1, %2" : "=v"(d) : "v"(a), "v"(b))

static __device__ __forceinline__ unsigned short f2b(float f){
  unsigned u = __float_as_uint(f);
  return (unsigned short)((u + 0x7FFFu + ((u>>16)&1u)) >> 16);  // RNE bf16
}

// ---------------------------------------------------------------------------
// prep: transpose points (B,CF,N)->(B,N,CF) and compute sq_xyz with rn ops
// ---------------------------------------------------------------------------
__global__ __launch_bounds__(256) void prep_kernel(const float* __restrict__ pts,
    const float* __restrict__ xyz, float* __restrict__ ptsT, float* __restrict__ sqx){
  int blk = blockIdx.x;            // 256 blocks = 16 b * 16 chunks
  int b = blk >> 4;
  int n = ((blk & 15) << 8) + threadIdx.x;
  const float* src = pts + (size_t)b*NCF*NN + n;
  float v[NCF];
  #pragma unroll
  for (int c=0;c<NCF;c++) v[c] = src[(size_t)c*NN];
  float4* dst = (float4*)(ptsT + ((size_t)b*NN + n)*NCF);
  #pragma unroll
  for (int j=0;j<16;j++) dst[j] = make_float4(v[4*j],v[4*j+1],v[4*j+2],v[4*j+3]);
  const float* xp = xyz + ((size_t)b*NN + n)*3;
  float x=xp[0], y=xp[1], z=xp[2];
  sqx[(size_t)b*NN+n] = fadd(fadd(fmul(x,x),fmul(y,y)),fmul(z,z));
}

// ---------------------------------------------------------------------------
// FPS: one block per batch, 512 threads, 8 pts/thread (4 packed pairs).
// Packed-f32 distance update; u64 key (f32bits<<32)|~n -> argmax w/ tie->lowest n.
// 5-stage butterfly per 32-half + 2 LDS atomicMax per wave; 1 barrier/step.
// ---------------------------------------------------------------------------
#define FT 512
__global__ __launch_bounds__(FT) void fps_kernel(const float* __restrict__ xyz,
    int* __restrict__ fidx, float* __restrict__ newxyz){
  int b = blockIdx.x;
  __shared__ float4 s4[NN];                 // 64 KB packed coords
  __shared__ unsigned long long slot[3];
  const int tid = threadIdx.x;
  for (int i = tid; i < NN; i += FT){
    const float* p = xyz + ((size_t)b*NN + i)*3;
    s4[i] = make_float4(p[0], p[1], p[2], 0.f);
  }
  if (tid < 3) slot[tid]=0ULL;
  __syncthreads();
  // pair m: .x -> n = tid + 512*(2m), .y -> n = tid + 512*(2m+1)
  f2 px[4], py[4], pz[4], d2[4];
  #pragma unroll
  for (int m=0;m<4;m++){
    float4 a = s4[tid + 1024*m];
    float4 c = s4[tid + 1024*m + 512];
    px[m] = (f2){a.x, c.x};
    py[m] = (f2){a.y, c.y};
    pz[m] = (f2){a.z, c.z};
    d2[m] = (f2){1e10f, 1e10f};
  }
  int far = 0;
  float4 cc = s4[0];
  for (int s=0;s<NS;s++){
    if (tid==0){
      fidx[b*NS+s] = far;
      float* o = newxyz + ((size_t)b*NS+s)*3;
      o[0]=cc.x; o[1]=cc.y; o[2]=cc.z;
      slot[(s+1)%3] = 0ULL;   // slot last consumed at step s-2; safe past barrier(s-1)
    }
    f2 ncx = (f2){-cc.x,-cc.x}, ncy = (f2){-cc.y,-cc.y}, ncz = (f2){-cc.z,-cc.z};
    float bv = -1.0f; int bj = 0;
    #pragma unroll
    for (int m=0;m<4;m++){
      f2 dx,dy,dz,xx,yy,zz,ss,dd;
      PK_ADD(dx, px[m], ncx);             // = p - c  (rn sub per element)
      PK_ADD(dy, py[m], ncy);
      PK_ADD(dz, pz[m], ncz);
      PK_MUL(xx, dx, dx);
      PK_MUL(yy, dy, dy);
      PK_ADD(ss, xx, yy);                  // (dx2+dy2)
      PK_MUL(zz, dz, dz);
      PK_ADD(dd, ss, zz);                  // +dz2 — numpy order, rn each
      float u0 = fminf(d2[m].x, dd.x);
      float u1 = fminf(d2[m].y, dd.y);
      d2[m].x = u0; d2[m].y = u1;
      if (u0 > bv){ bv = u0; bj = 2*m; }     // strict >: keeps lowest n on ties
      if (u1 > bv){ bv = u1; bj = 2*m+1; }
    }
    unsigned long long key = ((unsigned long long)__float_as_uint(bv) << 32)
                           | (unsigned long long)(unsigned)~(tid + (bj<<9));
    #pragma unroll
    for (int off=1; off<=16; off<<=1){
      unsigned long long o = __shfl_xor(key, off);
      if (o > key) key = o;
    }
    if ((tid & 31) == 0) atomicMax(&slot[s%3], key);
    __syncthreads();
    unsigned long long kk = slot[s%3];
    far = (int)(~(unsigned)kk) & (NN-1);
    cc = s4[far];
  }
}

__global__ __launch_bounds__(256) void dcen_kernel(const float* __restrict__ density,
    const int* __restrict__ fidx, float* __restrict__ dcen){
  int i = blockIdx.x*256 + threadIdx.x;   // 16384
  int b = i >> 10;
  dcen[i] = density[(size_t)b*NN + fidx[i]];
}

__global__ __launch_bounds__(256) void dstats_kernel(const float* __restrict__ dcen,
    float* __restrict__ dstat){
  float s=0.f, q=0.f;
  for (int i=threadIdx.x; i<NB*NS; i+=256){ float v=dcen[i]; s+=v; q+=v*v; }
  __shared__ float ls[256], lq[256];
  ls[threadIdx.x]=s; lq[threadIdx.x]=q;
  __syncthreads();
  for (int off=128; off>0; off>>=1){
    if (threadIdx.x<off){ ls[threadIdx.x]+=ls[threadIdx.x+off]; lq[threadIdx.x]+=lq[threadIdx.x+off]; }
    __syncthreads();
  }
  if (threadIdx.x==0){
    float m = ls[0]/(float)(NB*NS);
    dstat[0]=m; dstat[1]=lq[0]/(float)(NB*NS) - m*m;
  }
}

// ---------------------------------------------------------------------------
// kNN: one wave per center; wave-held top-32 in lanes 0..31 (empty = ~0ULL,
// lanes 32..63 hold 0). Key = sortable(d)<<32 | n -> exact (d, n) lex order.
// worst recomputed by 5-stage butterfly + shfl(.,0) broadcast; worstLane via
// ballot(kept==worst). Neighbor ORDER irrelevant downstream (perm-invariant).
// ---------------------------------------------------------------------------
__global__ __launch_bounds__(256) void knn_kernel(const float* __restrict__ xyz,
    const float* __restrict__ sqx, const float* __restrict__ newxyz,
    int* __restrict__ kidx){
  const int lane = threadIdx.x & 63;
  const int g = blockIdx.x*4 + (threadIdx.x >> 6);
  const int b = g >> 10;
  const float* cp = newxyz + (size_t)g*3;
  const float cx=cp[0], cy=cp[1], cz=cp[2];
  const float sqc = fadd(fadd(fmul(cx,cx),fmul(cy,cy)),fmul(cz,cz));
  const float* xb  = xyz + (size_t)b*NN*3;
  const float* sqb = sqx + (size_t)b*NN;
  unsigned long long kept  = (lane < 32) ? ~0ULL : 0ULL;
  unsigned long long worst = ~0ULL;
  int worstLane = 0;
  for (int n0=0; n0<NN; n0+=64){
    const int n = n0 + lane;
    const float* xp = xb + (size_t)n*3;
    float x=xp[0], y=xp[1], z=xp[2];
    float dot = fadd(fadd(fmul(cx,x),fmul(cy,y)),fmul(cz,z));
    float d = fsub(fadd(sqc, sqb[n]), fmul(2.0f,dot));
    unsigned u = __float_as_uint(d);
    u = (u & 0x80000000u) ? ~u : (u | 0x80000000u);   // total order incl. negatives
    unsigned long long ck = ((unsigned long long)u << 32) | (unsigned)n;
    unsigned long long mask = __ballot(ck < worst);
    while (mask){
      const int l = __ffsll((unsigned long long)mask) - 1;
      mask &= mask - 1;
      const unsigned long long k = __shfl(ck, l);
      if (k < worst){                       // uniform across wave
        if (lane == worstLane) kept = k;
        unsigned long long w = kept;
        #pragma unroll
        for (int off=1; off<=16; off<<=1){
          unsigned long long o = __shfl_xor(w, off);
          if (o > w) w = o;
        }
        worst = __shfl(w, 0);               // broadcast half-0 max to all 64
        unsigned long long mm = __ballot(kept == worst);
        worstLane = __ffsll((unsigned long long)mm) - 1;
      }
    }
  }
  if (lane < 32) kidx[(size_t)g*NK + lane] = (int)(kept & 0xFFFFFFFFULL);
}

// ---------------------------------------------------------------------------
// conv1: block=256, 128 pts, 2pts x 16outs per thread (unchanged numerics).
// ---------------------------------------------------------------------------
__global__ __launch_bounds__(256) void conv1_kernel(const float* __restrict__ xyz,
    const float* __restrict__ ptsT, const float* __restrict__ newxyz,
    const int* __restrict__ kidx, const float* __restrict__ w0,
    const float* __restrict__ b0, unsigned short* __restrict__ z1,
    float* __restrict__ partial){
  __shared__ float si[CIN][128];
  __shared__ float sw[CIN][64];
  __shared__ float sbias[64];
  const int tid = threadIdx.x;
  for (int i = tid; i < CIN*64; i += 256){
    int o = i / CIN, c = i - o*CIN;
    sw[c][o] = w0[i];
  }
  if (tid < 64) sbias[tid] = b0[tid];
  const int p0 = blockIdx.x * 128;
  if (tid < 128){
    const int p = p0 + tid;
    const int g = p >> 5;
    const int b = g >> 10;
    const int n = kidx[p];
    const float* xp = xyz + ((size_t)b*NN + n)*3;
    const float* cp = newxyz + (size_t)g*3;
    si[0][tid] = xp[0]-cp[0];
    si[1][tid] = xp[1]-cp[1];
    si[2][tid] = xp[2]-cp[2];
    const float4* pr = (const float4*)(ptsT + ((size_t)b*NN + n)*NCF);
    #pragma unroll
    for (int j=0;j<16;j++){
      float4 v = pr[j];
      si[3+4*j][tid]=v.x; si[4+4*j][tid]=v.y; si[5+4*j][tid]=v.z; si[6+4*j][tid]=v.w;
    }
  }
  __syncthreads();
  const int og = tid >> 6;     // wave id, 16 outputs
  const int pg = tid & 63;     // 2 points
  float acc0[16], acc1[16];
  #pragma unroll
  for (int j=0;j<16;j++){ float bv = sbias[og*16+j]; acc0[j]=bv; acc1[j]=bv; }
  for (int c=0;c<CIN;c++){
    float2 a = *(const float2*)&si[c][2*pg];
    const float4* wr = (const float4*)&sw[c][og*16];
    #pragma unroll
    for (int q=0;q<4;q++){
      float4 w = wr[q];
      acc0[4*q+0]+=a.x*w.x; acc0[4*q+1]+=a.x*w.y; acc0[4*q+2]+=a.x*w.z; acc0[4*q+3]+=a.x*w.w;
      acc1[4*q+0]+=a.y*w.x; acc1[4*q+1]+=a.y*w.y; acc1[4*q+2]+=a.y*w.z; acc1[4*q+3]+=a.y*w.w;
    }
  }
  unsigned v[8];
  #pragma unroll
  for (int j=0;j<8;j++) v[j] = (unsigned)f2b(acc0[2*j]) | ((unsigned)f2b(acc0[2*j+1])<<16);
  uint4* d0 = (uint4*)(z1 + (size_t)(p0+2*pg)*64 + og*16);
  d0[0]=make_uint4(v[0],v[1],v[2],v[3]); d0[1]=make_uint4(v[4],v[5],v[6],v[7]);
  #pragma unroll
  for (int j=0;j<8;j++) v[j] = (unsigned)f2b(acc1[2*j]) | ((unsigned)f2b(acc1[2*j+1])<<16);
  uint4* d1 = (uint4*)(z1 + (size_t)(p0+2*pg+1)*64 + og*16);
  d1[0]=make_uint4(v[0],v[1],v[2],v[3]); d1[1]=make_uint4(v[4],v[5],v[6],v[7]);
  #pragma unroll
  for (int j=0;j<16;j++){
    float s = acc0[j]+acc1[j];
    float q = acc0[j]*acc0[j] + acc1[j]*acc1[j];
    #pragma unroll
    for (int off=32; off>=1; off>>=1){ s += __shfl_xor(s,off); q += __shfl_xor(q,off); }
    if (pg==0){
      partial[(size_t)blockIdx.x*128 + og*16 + j] = s;
      partial[(size_t)blockIdx.x*128 + 64 + og*16 + j] = q;
    }
  }
}

__global__ __launch_bounds__(256) void conv2_kernel(const unsigned short* __restrict__ z1,
    const float* __restrict__ w1, const float* __restrict__ b1,
    const float* __restrict__ scale1, const float* __restrict__ shift1,
    unsigned short* __restrict__ z2, float* __restrict__ partial){
  __shared__ float si[64][128];
  __shared__ float sw[64][64];
  __shared__ float sbias[64];
  const int tid = threadIdx.x;
  for (int i = tid; i < 64*64; i += 256){
    int o = i >> 6, c = i & 63;
    sw[c][o] = w1[i];
  }
  if (tid < 64) sbias[tid] = b1[tid];
  const int p0 = blockIdx.x * 128;
  if (tid < 128){
    const uint4* zr = (const uint4*)(z1 + (size_t)(p0 + tid)*64);
    #pragma unroll
    for (int j=0;j<8;j++){
      uint4 vv = zr[j];
      unsigned a[4] = {vv.x, vv.y, vv.z, vv.w};
      #pragma unroll
      for (int t=0;t<4;t++){
        int c = j*8 + t*2;
        float lo = __uint_as_float(a[t] << 16);
        float hi = __uint_as_float(a[t] & 0xFFFF0000u);
        si[c][tid]   = fmaxf(lo*scale1[c]   + shift1[c],   0.0f);
        si[c+1][tid] = fmaxf(hi*scale1[c+1] + shift1[c+1], 0.0f);
      }
    }
  }
  __syncthreads();
  const int og = tid >> 6;
  const int pg = tid & 63;
  float acc0[16], acc1[16];
  #pragma unroll
  for (int j=0;j<16;j++){ float bv = sbias[og*16+j]; acc0[j]=bv; acc1[j]=bv; }
  for (int c=0;c<64;c++){
    float2 a = *(const float2*)&si[c][2*pg];
    const float4* wr = (const float4*)&sw[c][og*16];
    #pragma unroll
    for (int q=0;q<4;q++){
      float4 w = wr[q];
      acc0[4*q+0]+=a.x*w.x; acc0[4*q+1]+=a.x*w.y; acc0[4*q+2]+=a.x*w.z; acc0[4*q+3]+=a.x*w.w;
      acc1[4*q+0]+=a.y*w.x; acc1[4*q+1]+=a.y*w.y; acc1[4*q+2]+=a.y*w.z; acc1[4*q+3]+=a.y*w.w;
    }
  }
  unsigned v[8];
  #pragma unroll
  for (int j=0;j<8;j++) v[j] = (unsigned)f2b(acc0[2*j]) | ((unsigned)f2b(acc0[2*j+1])<<16);
  uint4* d0 = (uint4*)(z2 + (size_t)(p0+2*pg)*64 + og*16);
  d0[0]=make_uint4(v[0],v[1],v[2],v[3]); d0[1]=make_uint4(v[4],v[5],v[6],v[7]);
  #pragma unroll
  for (int j=0;j<8;j++) v[j] = (unsigned)f2b(acc1[2*j]) | ((unsigned)f2b(acc1[2*j+1])<<16);
  uint4* d1 = (uint4*)(z2 + (size_t)(p0+2*pg+1)*64 + og*16);
  d1[0]=make_uint4(v[0],v[1],v[2],v[3]); d1[1]=make_uint4(v[4],v[5],v[6],v[7]);
  #pragma unroll
  for (int j=0;j<16;j++){
    float s = acc0[j]+acc1[j];
    float q = acc0[j]*acc0[j] + acc1[j]*acc1[j];
    #pragma unroll
    for (int off=32; off>=1; off>>=1){ s += __shfl_xor(s,off); q += __shfl_xor(q,off); }
    if (pg==0){
      partial[(size_t)blockIdx.x*128 + og*16 + j] = s;
      partial[(size_t)blockIdx.x*128 + 64 + og*16 + j] = q;
    }
  }
}

// conv3: 128 pts (4 centers)/block, 4pts x 16outs per thread -> 64 FMA per
// 5 LDS reads. Max over k fused pre-BN (BN3 scale>0, density weight>=0).
__global__ __launch_bounds__(256) void conv3_kernel(const unsigned short* __restrict__ z2,
    const float* __restrict__ w2, const float* __restrict__ b2,
    const float* __restrict__ scale2, const float* __restrict__ shift2,
    float* __restrict__ m3, float* __restrict__ partial){
  __shared__ float si[64][128];
  __shared__ float sw[64][128];
  const int tid = threadIdx.x;
  for (int i = tid; i < 64*128; i += 256){
    int o = i >> 6, c = i & 63;
    sw[c][o] = w2[i];
  }
  const int p0 = blockIdx.x * 128;     // grid 4096
  if (tid < 128){
    const uint4* zr = (const uint4*)(z2 + (size_t)(p0 + tid)*64);
    #pragma unroll
    for (int j=0;j<8;j++){
      uint4 vv = zr[j];
      unsigned a[4]={vv.x,vv.y,vv.z,vv.w};
      #pragma unroll
      for (int t=0;t<4;t++){
        int c = j*8+t*2;
        float lo=__uint_as_float(a[t]<<16), hi=__uint_as_float(a[t]&0xFFFF0000u);
        si[c][tid]   = fmaxf(lo*scale2[c]+shift2[c],0.f);
        si[c+1][tid] = fmaxf(hi*scale2[c+1]+shift2[c+1],0.f);
      }
    }
  }
  __syncthreads();
  const int og = tid >> 5;    // 0..7 -> outputs og*16..+15
  const int pg = tid & 31;    // 4 pts: p0 + pg*4 .. +3 (center = pg>>3)
  float acc[4][16];
  const float4* bq = (const float4*)(b2 + og*16);
  #pragma unroll
  for (int q=0;q<4;q++){
    float4 bb = bq[q];
    #pragma unroll
    for (int p=0;p<4;p++){ acc[p][4*q]=bb.x; acc[p][4*q+1]=bb.y; acc[p][4*q+2]=bb.z; acc[p][4*q+3]=bb.w; }
  }
  for (int c=0;c<64;c++){
    float4 a = *(const float4*)&si[c][pg*4];
    const float4* wr = (const float4*)&sw[c][og*16];
    float ap[4] = {a.x, a.y, a.z, a.w};
    #pragma unroll
    for (int q=0;q<4;q++){
      float4 w = wr[q];
      #pragma unroll
      for (int p=0;p<4;p++){
        acc[p][4*q+0]+=ap[p]*w.x; acc[p][4*q+1]+=ap[p]*w.y;
        acc[p][4*q+2]+=ap[p]*w.z; acc[p][4*q+3]+=ap[p]*w.w;
      }
    }
  }
  float mx[16];
  #pragma unroll
  for (int j=0;j<16;j++){
    float m = fmaxf(fmaxf(acc[0][j],acc[1][j]), fmaxf(acc[2][j],acc[3][j]));
    #pragma unroll
    for (int off=1; off<=4; off<<=1) m = fmaxf(m, __shfl_xor(m, off));  // 8-lane group = 1 center
    mx[j]=m;
  }
  if ((pg & 7)==0){
    const int center = blockIdx.x*4 + (pg>>3);
    float4* mp = (float4*)(m3 + (size_t)center*128 + og*16);
    #pragma unroll
    for (int q=0;q<4;q++) mp[q] = make_float4(mx[4*q],mx[4*q+1],mx[4*q+2],mx[4*q+3]);
  }
  #pragma unroll
  for (int j=0;j<16;j++){
    float s = acc[0][j]+acc[1][j]+acc[2][j]+acc[3][j];
    float q = acc[0][j]*acc[0][j]+acc[1][j]*acc[1][j]+acc[2][j]*acc[2][j]+acc[3][j]*acc[3][j];
    #pragma unroll
    for (int off=1; off<=16; off<<=1){ s+=__shfl_xor(s,off); q+=__shfl_xor(q,off); }
    if (pg==0){
      partial[(size_t)blockIdx.x*256 + og*16 + j] = s;
      partial[(size_t)blockIdx.x*256 + 128 + og*16 + j] = q;
    }
  }
}

// reduce per-block partials -> BN scale/shift per channel (one block per channel)
__global__ __launch_bounds__(256) void mkbn_kernel(const float* __restrict__ partial,
    int nrows, int stride, const float* __restrict__ g, const float* __restrict__ be,
    float* __restrict__ scale, float* __restrict__ shift, float inv_count){
  const int c = blockIdx.x;
  const int C = gridDim.x;
  float s=0.f, q=0.f;
  for (int r=threadIdx.x; r<nrows; r+=256){
    s += partial[(size_t)r*stride + c];
    q += partial[(size_t)r*stride + C + c];
  }
  __shared__ float ls[256], lq[256];
  ls[threadIdx.x]=s; lq[threadIdx.x]=q;
  __syncthreads();
  for (int off=128; off>0; off>>=1){
    if (threadIdx.x < off){ ls[threadIdx.x]+=ls[threadIdx.x+off]; lq[threadIdx.x]+=lq[threadIdx.x+off]; }
    __syncthreads();
  }
  if (threadIdx.x==0){
    float mean = ls[0]*inv_count;
    float var  = lq[0]*inv_count - mean*mean;
    float sc = g[c]*rsqrtf(var + EPSV);
    scale[c]=sc; shift[c]=be[c]-mean*sc;
  }
}

// out[b,ch,s] = relu(scale3*maxz + shift3) * relu(bn_d(wd*dcen+bd))
__global__ __launch_bounds__(256) void final_kernel(const float* __restrict__ m3,
    const float* __restrict__ dcen, const float* __restrict__ scale3,
    const float* __restrict__ shift3, const float* __restrict__ wd,
    const float* __restrict__ bd, const float* __restrict__ gd,
    const float* __restrict__ bed, const float* __restrict__ dstat,
    float* __restrict__ out){
  size_t i = (size_t)blockIdx.x*256 + threadIdx.x;   // 2,097,152 = b*2^17 + ch*2^10 + s
  int s  = (int)(i & 1023);
  int ch = (int)((i >> 10) & 127);
  int b  = (int)(i >> 17);
  float mean_d = dstat[0], var_d = dstat[1];
  float w = wd[ch];
  float meanp = w*mean_d + bd[ch];
  float varp  = w*w*var_d;          // var of affine(dcen): exact algebraic identity
  float dsc = gd[ch]*rsqrtf(varp + EPSV);
  float dsh = bed[ch] - meanp*dsc;
  float pre = w*dcen[b*NS+s] + bd[ch];
  float dw  = fmaxf(dsc*pre + dsh, 0.0f);
  float z   = m3[((size_t)(b*NS+s))*128 + ch];
  float x   = fmaxf(scale3[ch]*z + shift3[ch], 0.0f);
  out[i] = x*dw;
}

// ---------------------------------------------------------------------------
extern "C" void kernel_launch(void* const* d_in, const int* in_sizes, int n_in,
                              void* d_out, int out_size, void* d_ws, size_t ws_size,
                              hipStream_t stream){
  const float* xyz     = (const float*)d_in[0];
  const float* points  = (const float*)d_in[1];
  const float* density = (const float*)d_in[2];
  const float* w0 = (const float*)d_in[3];
  const float* b0 = (const float*)d_in[4];
  const float* g0 = (const float*)d_in[5];
  const float* be0= (const float*)d_in[6];
  const float* w1 = (const float*)d_in[7];
  const float* b1 = (const float*)d_in[8];
  const float* g1 = (const float*)d_in[9];
  const float* be1= (const float*)d_in[10];
  const float* w2 = (const float*)d_in[11];
  const float* b2 = (const float*)d_in[12];
  const float* g2 = (const float*)d_in[13];
  const float* be2= (const float*)d_in[14];
  const float* wd = (const float*)d_in[15];
  const float* bd = (const float*)d_in[16];
  const float* gd = (const float*)d_in[17];
  const float* bed= (const float*)d_in[18];

  float* out = (float*)d_out;
  float* newxyz = out;                 // (B,S,3) = output 0
  float* out1   = out + (size_t)NB*NS*3;

  // workspace layout (~174 MB total)
  float* ptsT = (float*)d_ws;                            // 4,194,304 f
  float* sqx  = ptsT + (size_t)NB*NN*NCF;                // 65,536 f
  int*   fidx = (int*)(sqx + (size_t)NB*NN);             // 16,384 i
  float* dcen = (float*)(fidx + NB*NS);                  // 16,384 f
  int*   kidx = (int*)(dcen + NB*NS);                    // 524,288 i
  unsigned short* z1 = (unsigned short*)(kidx + NPTS);   // 33,554,432 us
  unsigned short* z2 = z1 + (size_t)NPTS*64;             // 33,554,432 us
  float* m3   = (float*)(z2 + (size_t)NPTS*64);          // 2,097,152 f
  float* p1   = m3 + (size_t)NB*NS*128;                  // 4096*128 f
  float* p2   = p1 + 4096*128;                           // 4096*128 f
  float* p3   = p2 + 4096*128;                           // 4096*256 f
  float* bnp  = p3 + 4096*256;                           // 512 f (scale/shift x3)
  float* dstat= bnp + 512;                               // 2 f

  hipLaunchKernelGGL(prep_kernel,  dim3(256),  dim3(256), 0, stream, points, xyz, ptsT, sqx);
  hipLaunchKernelGGL(fps_kernel,   dim3(NB),   dim3(FT),  0, stream, xyz, fidx, newxyz);
  hipLaunchKernelGGL(dcen_kernel,  dim3(64),   dim3(256), 0, stream, density, fidx, dcen);
  hipLaunchKernelGGL(dstats_kernel,dim3(1),    dim3(256), 0, stream, dcen, dstat);
  hipLaunchKernelGGL(knn_kernel,   dim3(4096), dim3(256), 0, stream, xyz, sqx, newxyz, kidx);
  hipLaunchKernelGGL(conv1_kernel, dim3(4096), dim3(256), 0, stream, xyz, ptsT, newxyz, kidx, w0, b0, z1, p1);
  hipLaunchKernelGGL(mkbn_kernel,  dim3(64),   dim3(256), 0, stream, p1, 4096, 128, g0, be0, bnp+0,   bnp+64,  1.0f/(float)NPTS);
  hipLaunchKernelGGL(conv2_kernel, dim3(4096), dim3(256), 0, stream, z1, w1, b1, bnp+0, bnp+64, z2, p2);
  hipLaunchKernelGGL(mkbn_kernel,  dim3(64),   dim3(256), 0, stream, p2, 4096, 128, g1, be1, bnp+128, bnp+192, 1.0f/(float)NPTS);
  hipLaunchKernelGGL(conv3_kernel, dim3(4096), dim3(256), 0, stream, z2, w2, b2, bnp+128, bnp+192, m3, p3);
  hipLaunchKernelGGL(mkbn_kernel,  dim3(128),  dim3(256), 0, stream, p3, 4096, 256, g2, be2, bnp+256, bnp+384, 1.0f/(float)NPTS);
  hipLaunchKernelGGL(final_kernel, dim3(8192), dim3(256), 0, stream, m3, dcen, bnp+256, bnp+384, wd, bd, gd, bed, dstat, out1);
}

// Round 3
// 1877.774 us; speedup vs baseline: 1.4246x; 1.0464x over previous
//
#include <hip/hip_runtime.h>
#include <hip/hip_bf16.h>
#include <stdint.h>

// Problem constants (fixed by the reference)
#define NB 16
#define NN 4096
#define NCF 64
#define NS 1024
#define NK 32
#define NPTS (NB*NS*NK)   // 524288
#define CIN 67
#define EPSV 1e-5f

// rn intrinsics: block FMA contraction so FPS/kNN distances bit-match numpy
static __device__ __forceinline__ float fmul(float a, float b){ return __fmul_rn(a,b); }
static __device__ __forceinline__ float fadd(float a, float b){ return __fadd_rn(a,b); }
static __device__ __forceinline__ float fsub(float a, float b){ return __fsub_rn(a,b); }

typedef float f2 __attribute__((ext_vector_type(2)));
// Packed f32 ops (VOP3P): per-element rn add/mul, identical semantics to
// scalar v_add_f32/v_mul_f32 — safe for the exact-index FPS recipe.
#define PK_ADD(d,a,b) asm("v_pk_add_f32 %0, %1, %2" : "=v"(d) : "v"(a), "v"(b))
#define PK_MUL(d,a,b) asm("v_pk_mul_f32 %0, %1, %2" : "=v"(d) : "v"(a), "v"(b))

static __device__ __forceinline__ unsigned short f2b(float f){
  unsigned u = __float_as_uint(f);
  return (unsigned short)((u + 0x7FFFu + ((u>>16)&1u)) >> 16);  // RNE bf16
}

static __device__ __forceinline__ unsigned long long umax64(unsigned long long a,
                                                            unsigned long long b){
  return a > b ? a : b;
}

// ---------------------------------------------------------------------------
// prep: transpose points (B,CF,N)->(B,N,CF) and compute sq_xyz with rn ops
// ---------------------------------------------------------------------------
__global__ __launch_bounds__(256) void prep_kernel(const float* __restrict__ pts,
    const float* __restrict__ xyz, float* __restrict__ ptsT, float* __restrict__ sqx){
  int blk = blockIdx.x;            // 256 blocks = 16 b * 16 chunks
  int b = blk >> 4;
  int n = ((blk & 15) << 8) + threadIdx.x;
  const float* src = pts + (size_t)b*NCF*NN + n;
  float v[NCF];
  #pragma unroll
  for (int c=0;c<NCF;c++) v[c] = src[(size_t)c*NN];
  float4* dst = (float4*)(ptsT + ((size_t)b*NN + n)*NCF);
  #pragma unroll
  for (int j=0;j<16;j++) dst[j] = make_float4(v[4*j],v[4*j+1],v[4*j+2],v[4*j+3]);
  const float* xp = xyz + ((size_t)b*NN + n)*3;
  float x=xp[0], y=xp[1], z=xp[2];
  sqx[(size_t)b*NN+n] = fadd(fadd(fmul(x,x),fmul(y,y)),fmul(z,z));
}

// ---------------------------------------------------------------------------
// FPS: one block per batch, 256 threads (4 waves, 1 wave/SIMD), 16 pts/thread
// (8 packed pairs). Per step: packed rn distance update -> running (bv,bj)
// argmax (strict >, ascending local n => first occurrence) -> u64 key
// (f32bits<<32)|~n -> 5-stage 32-lane butterfly -> 8 half-group leaders
// ds_write_b64 to DISTINCT parity-buffered slots (no atomics, no reset) ->
// one barrier -> every thread reads 8 cands (4x b128) + 3-deep u64 max tree.
// Exact np.argmax semantics (max value, tie -> lowest index).
// ---------------------------------------------------------------------------
#define FT 256
__global__ __launch_bounds__(FT) void fps_kernel(const float* __restrict__ xyz,
    int* __restrict__ fidx, float* __restrict__ newxyz){
  int b = blockIdx.x;
  __shared__ float4 s4[NN];                       // 64 KB packed coords
  __shared__ unsigned long long cand[2][8];       // parity-double-buffered
  const int tid = threadIdx.x;
  for (int i = tid; i < NN; i += FT){
    const float* p = xyz + ((size_t)b*NN + i)*3;
    s4[i] = make_float4(p[0], p[1], p[2], 0.f);
  }
  __syncthreads();
  // pair m: .x -> n = tid + 512m, .y -> n = tid + 512m + 256
  f2 px[8], py[8], pz[8], d2[8];
  #pragma unroll
  for (int m=0;m<8;m++){
    float4 a = s4[tid + 512*m];
    float4 c = s4[tid + 512*m + 256];
    px[m] = (f2){a.x, c.x};
    py[m] = (f2){a.y, c.y};
    pz[m] = (f2){a.z, c.z};
    d2[m] = (f2){1e10f, 1e10f};
  }
  int far = 0;
  float4 cc = s4[0];
  for (int s=0;s<NS;s++){
    if (tid==0){
      fidx[b*NS+s] = far;
      float* o = newxyz + ((size_t)b*NS+s)*3;
      o[0]=cc.x; o[1]=cc.y; o[2]=cc.z;
    }
    f2 ncx = (f2){-cc.x,-cc.x}, ncy = (f2){-cc.y,-cc.y}, ncz = (f2){-cc.z,-cc.z};
    float bv = -1.0f; int bj = 0;
    #pragma unroll
    for (int m=0;m<8;m++){
      f2 dx,dy,dz,xx,yy,zz,ss,dd;
      PK_ADD(dx, px[m], ncx);              // = p - c  (rn sub per element)
      PK_ADD(dy, py[m], ncy);
      PK_ADD(dz, pz[m], ncz);
      PK_MUL(xx, dx, dx);
      PK_MUL(yy, dy, dy);
      PK_ADD(ss, xx, yy);                  // (dx2+dy2)
      PK_MUL(zz, dz, dz);
      PK_ADD(dd, ss, zz);                  // +dz2 — numpy order, rn each
      float u0 = fminf(d2[m].x, dd.x);
      float u1 = fminf(d2[m].y, dd.y);
      d2[m].x = u0; d2[m].y = u1;
      if (u0 > bv){ bv = u0; bj = 2*m; }   // strict >: keeps lowest local n
      if (u1 > bv){ bv = u1; bj = 2*m+1; }
    }
    unsigned n = (unsigned)tid + ((unsigned)bj<<8);
    unsigned long long key = ((unsigned long long)__float_as_uint(bv) << 32)
                           | (unsigned long long)(unsigned)~n;
    #pragma unroll
    for (int off=1; off<=16; off<<=1){
      unsigned long long o = __shfl_xor(key, off);
      if (o > key) key = o;
    }
    if ((tid & 31) == 0) cand[s&1][tid>>5] = key;
    __syncthreads();
    const ulonglong2* cp = (const ulonglong2*)cand[s&1];
    ulonglong2 c0=cp[0], c1=cp[1], c2=cp[2], c3=cp[3];
    unsigned long long kk = umax64(
        umax64(umax64(c0.x,c0.y), umax64(c1.x,c1.y)),
        umax64(umax64(c2.x,c2.y), umax64(c3.x,c3.y)));
    far = (int)(~(unsigned)kk) & (NN-1);
    cc = s4[far];
  }
}

__global__ __launch_bounds__(256) void dcen_kernel(const float* __restrict__ density,
    const int* __restrict__ fidx, float* __restrict__ dcen){
  int i = blockIdx.x*256 + threadIdx.x;   // 16384
  int b = i >> 10;
  dcen[i] = density[(size_t)b*NN + fidx[i]];
}

__global__ __launch_bounds__(256) void dstats_kernel(const float* __restrict__ dcen,
    float* __restrict__ dstat){
  float s=0.f, q=0.f;
  for (int i=threadIdx.x; i<NB*NS; i+=256){ float v=dcen[i]; s+=v; q+=v*v; }
  __shared__ float ls[256], lq[256];
  ls[threadIdx.x]=s; lq[threadIdx.x]=q;
  __syncthreads();
  for (int off=128; off>0; off>>=1){
    if (threadIdx.x<off){ ls[threadIdx.x]+=ls[threadIdx.x+off]; lq[threadIdx.x]+=lq[threadIdx.x+off]; }
    __syncthreads();
  }
  if (threadIdx.x==0){
    float m = ls[0]/(float)(NB*NS);
    dstat[0]=m; dstat[1]=lq[0]/(float)(NB*NS) - m*m;
  }
}

// ---------------------------------------------------------------------------
// kNN: one wave per center; wave-held top-32 in lanes 0..31 (empty = ~0ULL,
// lanes 32..63 hold 0). Key = sortable(d)<<32 | n -> exact (d, n) lex order.
// worst recomputed by 5-stage butterfly + shfl(.,0) broadcast; worstLane via
// ballot(kept==worst). Neighbor ORDER irrelevant downstream (perm-invariant).
// ---------------------------------------------------------------------------
__global__ __launch_bounds__(256) void knn_kernel(const float* __restrict__ xyz,
    const float* __restrict__ sqx, const float* __restrict__ newxyz,
    int* __restrict__ kidx){
  const int lane = threadIdx.x & 63;
  const int g = blockIdx.x*4 + (threadIdx.x >> 6);
  const int b = g >> 10;
  const float* cp = newxyz + (size_t)g*3;
  const float cx=cp[0], cy=cp[1], cz=cp[2];
  const float sqc = fadd(fadd(fmul(cx,cx),fmul(cy,cy)),fmul(cz,cz));
  const float* xb  = xyz + (size_t)b*NN*3;
  const float* sqb = sqx + (size_t)b*NN;
  unsigned long long kept  = (lane < 32) ? ~0ULL : 0ULL;
  unsigned long long worst = ~0ULL;
  int worstLane = 0;
  for (int n0=0; n0<NN; n0+=64){
    const int n = n0 + lane;
    const float* xp = xb + (size_t)n*3;
    float x=xp[0], y=xp[1], z=xp[2];
    float dot = fadd(fadd(fmul(cx,x),fmul(cy,y)),fmul(cz,z));
    float d = fsub(fadd(sqc, sqb[n]), fmul(2.0f,dot));
    unsigned u = __float_as_uint(d);
    u = (u & 0x80000000u) ? ~u : (u | 0x80000000u);   // total order incl. negatives
    unsigned long long ck = ((unsigned long long)u << 32) | (unsigned)n;
    unsigned long long mask = __ballot(ck < worst);
    while (mask){
      const int l = __ffsll((unsigned long long)mask) - 1;
      mask &= mask - 1;
      const unsigned long long k = __shfl(ck, l);
      if (k < worst){                       // uniform across wave
        if (lane == worstLane) kept = k;
        unsigned long long w = kept;
        #pragma unroll
        for (int off=1; off<=16; off<<=1){
          unsigned long long o = __shfl_xor(w, off);
          if (o > w) w = o;
        }
        worst = __shfl(w, 0);               // broadcast half-0 max to all 64
        unsigned long long mm = __ballot(kept == worst);
        worstLane = __ffsll((unsigned long long)mm) - 1;
      }
    }
  }
  if (lane < 32) kidx[(size_t)g*NK + lane] = (int)(kept & 0xFFFFFFFFULL);
}

// ---------------------------------------------------------------------------
// conv1: block=256, 128 pts, 2pts x 16outs per thread (unchanged numerics).
// ---------------------------------------------------------------------------
__global__ __launch_bounds__(256) void conv1_kernel(const float* __restrict__ xyz,
    const float* __restrict__ ptsT, const float* __restrict__ newxyz,
    const int* __restrict__ kidx, const float* __restrict__ w0,
    const float* __restrict__ b0, unsigned short* __restrict__ z1,
    float* __restrict__ partial){
  __shared__ float si[CIN][128];
  __shared__ float sw[CIN][64];
  __shared__ float sbias[64];
  const int tid = threadIdx.x;
  for (int i = tid; i < CIN*64; i += 256){
    int o = i / CIN, c = i - o*CIN;
    sw[c][o] = w0[i];
  }
  if (tid < 64) sbias[tid] = b0[tid];
  const int p0 = blockIdx.x * 128;
  if (tid < 128){
    const int p = p0 + tid;
    const int g = p >> 5;
    const int b = g >> 10;
    const int n = kidx[p];
    const float* xp = xyz + ((size_t)b*NN + n)*3;
    const float* cp = newxyz + (size_t)g*3;
    si[0][tid] = xp[0]-cp[0];
    si[1][tid] = xp[1]-cp[1];
    si[2][tid] = xp[2]-cp[2];
    const float4* pr = (const float4*)(ptsT + ((size_t)b*NN + n)*NCF);
    #pragma unroll
    for (int j=0;j<16;j++){
      float4 v = pr[j];
      si[3+4*j][tid]=v.x; si[4+4*j][tid]=v.y; si[5+4*j][tid]=v.z; si[6+4*j][tid]=v.w;
    }
  }
  __syncthreads();
  const int og = tid >> 6;     // wave id, 16 outputs
  const int pg = tid & 63;     // 2 points
  float acc0[16], acc1[16];
  #pragma unroll
  for (int j=0;j<16;j++){ float bv = sbias[og*16+j]; acc0[j]=bv; acc1[j]=bv; }
  for (int c=0;c<CIN;c++){
    float2 a = *(const float2*)&si[c][2*pg];
    const float4* wr = (const float4*)&sw[c][og*16];
    #pragma unroll
    for (int q=0;q<4;q++){
      float4 w = wr[q];
      acc0[4*q+0]+=a.x*w.x; acc0[4*q+1]+=a.x*w.y; acc0[4*q+2]+=a.x*w.z; acc0[4*q+3]+=a.x*w.w;
      acc1[4*q+0]+=a.y*w.x; acc1[4*q+1]+=a.y*w.y; acc1[4*q+2]+=a.y*w.z; acc1[4*q+3]+=a.y*w.w;
    }
  }
  unsigned v[8];
  #pragma unroll
  for (int j=0;j<8;j++) v[j] = (unsigned)f2b(acc0[2*j]) | ((unsigned)f2b(acc0[2*j+1])<<16);
  uint4* d0 = (uint4*)(z1 + (size_t)(p0+2*pg)*64 + og*16);
  d0[0]=make_uint4(v[0],v[1],v[2],v[3]); d0[1]=make_uint4(v[4],v[5],v[6],v[7]);
  #pragma unroll
  for (int j=0;j<8;j++) v[j] = (unsigned)f2b(acc1[2*j]) | ((unsigned)f2b(acc1[2*j+1])<<16);
  uint4* d1 = (uint4*)(z1 + (size_t)(p0+2*pg+1)*64 + og*16);
  d1[0]=make_uint4(v[0],v[1],v[2],v[3]); d1[1]=make_uint4(v[4],v[5],v[6],v[7]);
  #pragma unroll
  for (int j=0;j<16;j++){
    float s = acc0[j]+acc1[j];
    float q = acc0[j]*acc0[j] + acc1[j]*acc1[j];
    #pragma unroll
    for (int off=32; off>=1; off>>=1){ s += __shfl_xor(s,off); q += __shfl_xor(q,off); }
    if (pg==0){
      partial[(size_t)blockIdx.x*128 + og*16 + j] = s;
      partial[(size_t)blockIdx.x*128 + 64 + og*16 + j] = q;
    }
  }
}

__global__ __launch_bounds__(256) void conv2_kernel(const unsigned short* __restrict__ z1,
    const float* __restrict__ w1, const float* __restrict__ b1,
    const float* __restrict__ scale1, const float* __restrict__ shift1,
    unsigned short* __restrict__ z2, float* __restrict__ partial){
  __shared__ float si[64][128];
  __shared__ float sw[64][64];
  __shared__ float sbias[64];
  const int tid = threadIdx.x;
  for (int i = tid; i < 64*64; i += 256){
    int o = i >> 6, c = i & 63;
    sw[c][o] = w1[i];
  }
  if (tid < 64) sbias[tid] = b1[tid];
  const int p0 = blockIdx.x * 128;
  if (tid < 128){
    const uint4* zr = (const uint4*)(z1 + (size_t)(p0 + tid)*64);
    #pragma unroll
    for (int j=0;j<8;j++){
      uint4 vv = zr[j];
      unsigned a[4] = {vv.x, vv.y, vv.z, vv.w};
      #pragma unroll
      for (int t=0;t<4;t++){
        int c = j*8 + t*2;
        float lo = __uint_as_float(a[t] << 16);
        float hi = __uint_as_float(a[t] & 0xFFFF0000u);
        si[c][tid]   = fmaxf(lo*scale1[c]   + shift1[c],   0.0f);
        si[c+1][tid] = fmaxf(hi*scale1[c+1] + shift1[c+1], 0.0f);
      }
    }
  }
  __syncthreads();
  const int og = tid >> 6;
  const int pg = tid & 63;
  float acc0[16], acc1[16];
  #pragma unroll
  for (int j=0;j<16;j++){ float bv = sbias[og*16+j]; acc0[j]=bv; acc1[j]=bv; }
  for (int c=0;c<64;c++){
    float2 a = *(const float2*)&si[c][2*pg];
    const float4* wr = (const float4*)&sw[c][og*16];
    #pragma unroll
    for (int q=0;q<4;q++){
      float4 w = wr[q];
      acc0[4*q+0]+=a.x*w.x; acc0[4*q+1]+=a.x*w.y; acc0[4*q+2]+=a.x*w.z; acc0[4*q+3]+=a.x*w.w;
      acc1[4*q+0]+=a.y*w.x; acc1[4*q+1]+=a.y*w.y; acc1[4*q+2]+=a.y*w.z; acc1[4*q+3]+=a.y*w.w;
    }
  }
  unsigned v[8];
  #pragma unroll
  for (int j=0;j<8;j++) v[j] = (unsigned)f2b(acc0[2*j]) | ((unsigned)f2b(acc0[2*j+1])<<16);
  uint4* d0 = (uint4*)(z2 + (size_t)(p0+2*pg)*64 + og*16);
  d0[0]=make_uint4(v[0],v[1],v[2],v[3]); d0[1]=make_uint4(v[4],v[5],v[6],v[7]);
  #pragma unroll
  for (int j=0;j<8;j++) v[j] = (unsigned)f2b(acc1[2*j]) | ((unsigned)f2b(acc1[2*j+1])<<16);
  uint4* d1 = (uint4*)(z2 + (size_t)(p0+2*pg+1)*64 + og*16);
  d1[0]=make_uint4(v[0],v[1],v[2],v[3]); d1[1]=make_uint4(v[4],v[5],v[6],v[7]);
  #pragma unroll
  for (int j=0;j<16;j++){
    float s = acc0[j]+acc1[j];
    float q = acc0[j]*acc0[j] + acc1[j]*acc1[j];
    #pragma unroll
    for (int off=32; off>=1; off>>=1){ s += __shfl_xor(s,off); q += __shfl_xor(q,off); }
    if (pg==0){
      partial[(size_t)blockIdx.x*128 + og*16 + j] = s;
      partial[(size_t)blockIdx.x*128 + 64 + og*16 + j] = q;
    }
  }
}

// conv3: 128 pts (4 centers)/block, 4pts x 16outs per thread -> 64 FMA per
// 5 LDS reads. Max over k fused pre-BN (BN3 scale>0, density weight>=0).
__global__ __launch_bounds__(256) void conv3_kernel(const unsigned short* __restrict__ z2,
    const float* __restrict__ w2, const float* __restrict__ b2,
    const float* __restrict__ scale2, const float* __restrict__ shift2,
    float* __restrict__ m3, float* __restrict__ partial){
  __shared__ float si[64][128];
  __shared__ float sw[64][128];
  const int tid = threadIdx.x;
  for (int i = tid; i < 64*128; i += 256){
    int o = i >> 6, c = i & 63;
    sw[c][o] = w2[i];
  }
  const int p0 = blockIdx.x * 128;     // grid 4096
  if (tid < 128){
    const uint4* zr = (const uint4*)(z2 + (size_t)(p0 + tid)*64);
    #pragma unroll
    for (int j=0;j<8;j++){
      uint4 vv = zr[j];
      unsigned a[4]={vv.x,vv.y,vv.z,vv.w};
      #pragma unroll
      for (int t=0;t<4;t++){
        int c = j*8+t*2;
        float lo=__uint_as_float(a[t]<<16), hi=__uint_as_float(a[t]&0xFFFF0000u);
        si[c][tid]   = fmaxf(lo*scale2[c]+shift2[c],0.f);
        si[c+1][tid] = fmaxf(hi*scale2[c+1]+shift2[c+1],0.f);
      }
    }
  }
  __syncthreads();
  const int og = tid >> 5;    // 0..7 -> outputs og*16..+15
  const int pg = tid & 31;    // 4 pts: p0 + pg*4 .. +3 (center = pg>>3)
  float acc[4][16];
  const float4* bq = (const float4*)(b2 + og*16);
  #pragma unroll
  for (int q=0;q<4;q++){
    float4 bb = bq[q];
    #pragma unroll
    for (int p=0;p<4;p++){ acc[p][4*q]=bb.x; acc[p][4*q+1]=bb.y; acc[p][4*q+2]=bb.z; acc[p][4*q+3]=bb.w; }
  }
  for (int c=0;c<64;c++){
    float4 a = *(const float4*)&si[c][pg*4];
    const float4* wr = (const float4*)&sw[c][og*16];
    float ap[4] = {a.x, a.y, a.z, a.w};
    #pragma unroll
    for (int q=0;q<4;q++){
      float4 w = wr[q];
      #pragma unroll
      for (int p=0;p<4;p++){
        acc[p][4*q+0]+=ap[p]*w.x; acc[p][4*q+1]+=ap[p]*w.y;
        acc[p][4*q+2]+=ap[p]*w.z; acc[p][4*q+3]+=ap[p]*w.w;
      }
    }
  }
  float mx[16];
  #pragma unroll
  for (int j=0;j<16;j++){
    float m = fmaxf(fmaxf(acc[0][j],acc[1][j]), fmaxf(acc[2][j],acc[3][j]));
    #pragma unroll
    for (int off=1; off<=4; off<<=1) m = fmaxf(m, __shfl_xor(m, off));  // 8-lane group = 1 center
    mx[j]=m;
  }
  if ((pg & 7)==0){
    const int center = blockIdx.x*4 + (pg>>3);
    float4* mp = (float4*)(m3 + (size_t)center*128 + og*16);
    #pragma unroll
    for (int q=0;q<4;q++) mp[q] = make_float4(mx[4*q],mx[4*q+1],mx[4*q+2],mx[4*q+3]);
  }
  #pragma unroll
  for (int j=0;j<16;j++){
    float s = acc[0][j]+acc[1][j]+acc[2][j]+acc[3][j];
    float q = acc[0][j]*acc[0][j]+acc[1][j]*acc[1][j]+acc[2][j]*acc[2][j]+acc[3][j]*acc[3][j];
    #pragma unroll
    for (int off=1; off<=16; off<<=1){ s+=__shfl_xor(s,off); q+=__shfl_xor(q,off); }
    if (pg==0){
      partial[(size_t)blockIdx.x*256 + og*16 + j] = s;
      partial[(size_t)blockIdx.x*256 + 128 + og*16 + j] = q;
    }
  }
}

// reduce per-block partials -> BN scale/shift per channel (one block per channel)
__global__ __launch_bounds__(256) void mkbn_kernel(const float* __restrict__ partial,
    int nrows, int stride, const float* __restrict__ g, const float* __restrict__ be,
    float* __restrict__ scale, float* __restrict__ shift, float inv_count){
  const int c = blockIdx.x;
  const int C = gridDim.x;
  float s=0.f, q=0.f;
  for (int r=threadIdx.x; r<nrows; r+=256){
    s += partial[(size_t)r*stride + c];
    q += partial[(size_t)r*stride + C + c];
  }
  __shared__ float ls[256], lq[256];
  ls[threadIdx.x]=s; lq[threadIdx.x]=q;
  __syncthreads();
  for (int off=128; off>0; off>>=1){
    if (threadIdx.x < off){ ls[threadIdx.x]+=ls[threadIdx.x+off]; lq[threadIdx.x]+=lq[threadIdx.x+off]; }
    __syncthreads();
  }
  if (threadIdx.x==0){
    float mean = ls[0]*inv_count;
    float var  = lq[0]*inv_count - mean*mean;
    float sc = g[c]*rsqrtf(var + EPSV);
    scale[c]=sc; shift[c]=be[c]-mean*sc;
  }
}

// out[b,ch,s] = relu(scale3*maxz + shift3) * relu(bn_d(wd*dcen+bd))
__global__ __launch_bounds__(256) void final_kernel(const float* __restrict__ m3,
    const float* __restrict__ dcen, const float* __restrict__ scale3,
    const float* __restrict__ shift3, const float* __restrict__ wd,
    const float* __restrict__ bd, const float* __restrict__ gd,
    const float* __restrict__ bed, const float* __restrict__ dstat,
    float* __restrict__ out){
  size_t i = (size_t)blockIdx.x*256 + threadIdx.x;   // 2,097,152 = b*2^17 + ch*2^10 + s
  int s  = (int)(i & 1023);
  int ch = (int)((i >> 10) & 127);
  int b  = (int)(i >> 17);
  float mean_d = dstat[0], var_d = dstat[1];
  float w = wd[ch];
  float meanp = w*mean_d + bd[ch];
  float varp  = w*w*var_d;          // var of affine(dcen): exact algebraic identity
  float dsc = gd[ch]*rsqrtf(varp + EPSV);
  float dsh = bed[ch] - meanp*dsc;
  float pre = w*dcen[b*NS+s] + bd[ch];
  float dw  = fmaxf(dsc*pre + dsh, 0.0f);
  float z   = m3[((size_t)(b*NS+s))*128 + ch];
  float x   = fmaxf(scale3[ch]*z + shift3[ch], 0.0f);
  out[i] = x*dw;
}

// ---------------------------------------------------------------------------
extern "C" void kernel_launch(void* const* d_in, const int* in_sizes, int n_in,
                              void* d_out, int out_size, void* d_ws, size_t ws_size,
                              hipStream_t stream){
  const float* xyz     = (const float*)d_in[0];
  const float* points  = (const float*)d_in[1];
  const float* density = (const float*)d_in[2];
  const float* w0 = (const float*)d_in[3];
  const float* b0 = (const float*)d_in[4];
  const float* g0 = (const float*)d_in[5];
  const float* be0= (const float*)d_in[6];
  const float* w1 = (const float*)d_in[7];
  const float* b1 = (const float*)d_in[8];
  const float* g1 = (const float*)d_in[9];
  const float* be1= (const float*)d_in[10];
  const float* w2 = (const float*)d_in[11];
  const float* b2 = (const float*)d_in[12];
  const float* g2 = (const float*)d_in[13];
  const float* be2= (const float*)d_in[14];
  const float* wd = (const float*)d_in[15];
  const float* bd = (const float*)d_in[16];
  const float* gd = (const float*)d_in[17];
  const float* bed= (const float*)d_in[18];

  float* out = (float*)d_out;
  float* newxyz = out;                 // (B,S,3) = output 0
  float* out1   = out + (size_t)NB*NS*3;

  // workspace layout (~174 MB total)
  float* ptsT = (float*)d_ws;                            // 4,194,304 f
  float* sqx  = ptsT + (size_t)NB*NN*NCF;                // 65,536 f
  int*   fidx = (int*)(sqx + (size_t)NB*NN);             // 16,384 i
  float* dcen = (float*)(fidx + NB*NS);                  // 16,384 f
  int*   kidx = (int*)(dcen + NB*NS);                    // 524,288 i
  unsigned short* z1 = (unsigned short*)(kidx + NPTS);   // 33,554,432 us
  unsigned short* z2 = z1 + (size_t)NPTS*64;             // 33,554,432 us
  float* m3   = (float*)(z2 + (size_t)NPTS*64);          // 2,097,152 f
  float* p1   = m3 + (size_t)NB*NS*128;                  // 4096*128 f
  float* p2   = p1 + 4096*128;                           // 4096*128 f
  float* p3   = p2 + 4096*128;                           // 4096*256 f
  float* bnp  = p3 + 4096*256;                           // 512 f (scale/shift x3)
  float* dstat= bnp + 512;                               // 2 f

  hipLaunchKernelGGL(prep_kernel,  dim3(256),  dim3(256), 0, stream, points, xyz, ptsT, sqx);
  hipLaunchKernelGGL(fps_kernel,   dim3(NB),   dim3(FT),  0, stream, xyz, fidx, newxyz);
  hipLaunchKernelGGL(dcen_kernel,  dim3(64),   dim3(256), 0, stream, density, fidx, dcen);
  hipLaunchKernelGGL(dstats_kernel,dim3(1),    dim3(256), 0, stream, dcen, dstat);
  hipLaunchKernelGGL(knn_kernel,   dim3(4096), dim3(256), 0, stream, xyz, sqx, newxyz, kidx);
  hipLaunchKernelGGL(conv1_kernel, dim3(4096), dim3(256), 0, stream, xyz, ptsT, newxyz, kidx, w0, b0, z1, p1);
  hipLaunchKernelGGL(mkbn_kernel,  dim3(64),   dim3(256), 0, stream, p1, 4096, 128, g0, be0, bnp+0,   bnp+64,  1.0f/(float)NPTS);
  hipLaunchKernelGGL(conv2_kernel, dim3(4096), dim3(256), 0, stream, z1, w1, b1, bnp+0, bnp+64, z2, p2);
  hipLaunchKernelGGL(mkbn_kernel,  dim3(64),   dim3(256), 0, stream, p2, 4096, 128, g1, be1, bnp+128, bnp+192, 1.0f/(float)NPTS);
  hipLaunchKernelGGL(conv3_kernel, dim3(4096), dim3(256), 0, stream, z2, w2, b2, bnp+128, bnp+192, m3, p3);
  hipLaunchKernelGGL(mkbn_kernel,  dim3(128),  dim3(256), 0, stream, p3, 4096, 256, g2, be2, bnp+256, bnp+384, 1.0f/(float)NPTS);
  hipLaunchKernelGGL(final_kernel, dim3(8192), dim3(256), 0, stream, m3, dcen, bnp+256, bnp+384, wd, bd, gd, bed, dstat, out1);
}

// Round 4
// 1409.020 us; speedup vs baseline: 1.8985x; 1.3327x over previous
//
#include <hip/hip_runtime.h>
#include <hip/hip_bf16.h>
#include <stdint.h>

// Problem constants (fixed by the reference)
#define NB 16
#define NN 4096
#define NCF 64
#define NS 1024
#define NK 32
#define NPTS (NB*NS*NK)   // 524288
#define CIN 67
#define EPSV 1e-5f

// rn intrinsics: block FMA contraction so FPS/kNN distances bit-match numpy
static __device__ __forceinline__ float fmul(float a, float b){ return __fmul_rn(a,b); }
static __device__ __forceinline__ float fadd(float a, float b){ return __fadd_rn(a,b); }
static __device__ __forceinline__ float fsub(float a, float b){ return __fsub_rn(a,b); }

typedef float f2 __attribute__((ext_vector_type(2)));
// Packed f32 ops (VOP3P): per-element rn add/mul, identical semantics to
// scalar v_add_f32/v_mul_f32 — safe for the exact-index FPS recipe.
#define PK_ADD(d,a,b) asm("v_pk_add_f32 %0, %1, %2" : "=v"(d) : "v"(a), "v"(b))
#define PK_MUL(d,a,b) asm("v_pk_mul_f32 %0, %1, %2" : "=v"(d) : "v"(a), "v"(b))

static __device__ __forceinline__ unsigned short f2b(float f){
  unsigned u = __float_as_uint(f);
  return (unsigned short)((u + 0x7FFFu + ((u>>16)&1u)) >> 16);  // RNE bf16
}

static __device__ __forceinline__ unsigned long long umax64(unsigned long long a,
                                                            unsigned long long b){
  return a > b ? a : b;
}

// ---- DPP cross-lane reductions (pure VALU — no LDS latency) ----------------
// bound_ctrl=true: invalid lanes read 0 — identity for f32 max of >=0 values,
// f32 add, u32/u64 max of our keys.
template<int CTRL>
static __device__ __forceinline__ float dppmax_f32(float x){
  float o = __uint_as_float((unsigned)__builtin_amdgcn_update_dpp(
      0, (int)__float_as_uint(x), CTRL, 0xf, 0xf, true));
  return fmaxf(x, o);
}
// full-wave max -> valid in lane 63
static __device__ __forceinline__ float wave_max63_f32(float x){
  x = dppmax_f32<0x111>(x);  // row_shr:1
  x = dppmax_f32<0x112>(x);  // row_shr:2
  x = dppmax_f32<0x114>(x);  // row_shr:4
  x = dppmax_f32<0x118>(x);  // row_shr:8
  x = dppmax_f32<0x142>(x);  // row_bcast:15
  x = dppmax_f32<0x143>(x);  // row_bcast:31
  return x;
}
template<int CTRL>
static __device__ __forceinline__ float dppadd_f32(float x){
  float o = __uint_as_float((unsigned)__builtin_amdgcn_update_dpp(
      0, (int)__float_as_uint(x), CTRL, 0xf, 0xf, true));
  return x + o;
}
// full-wave sum -> valid in lane 63
static __device__ __forceinline__ float wave_sum63_f32(float x){
  x = dppadd_f32<0x111>(x);
  x = dppadd_f32<0x112>(x);
  x = dppadd_f32<0x114>(x);
  x = dppadd_f32<0x118>(x);
  x = dppadd_f32<0x142>(x);
  x = dppadd_f32<0x143>(x);
  return x;
}
// 32-half sum -> valid in lanes 31 and 63
static __device__ __forceinline__ float half_sum31_f32(float x){
  x = dppadd_f32<0x111>(x);
  x = dppadd_f32<0x112>(x);
  x = dppadd_f32<0x114>(x);
  x = dppadd_f32<0x118>(x);
  x = dppadd_f32<0x142>(x);  // row_bcast:15 -> lane31/63 hold 32-half totals
  return x;
}
// 8-lane-group max, result in ALL 8 lanes (quad_perm xor1, xor2, half_mirror)
static __device__ __forceinline__ float group8_max_f32(float x){
  x = dppmax_f32<0xB1>(x);   // quad_perm [1,0,3,2]
  x = dppmax_f32<0x4E>(x);   // quad_perm [2,3,0,1]
  x = dppmax_f32<0x141>(x);  // row_half_mirror
  return x;
}
template<int CTRL>
static __device__ __forceinline__ unsigned long long dppmax_u64(unsigned long long x){
  unsigned lo = (unsigned)__builtin_amdgcn_update_dpp(
      0, (int)(unsigned)x, CTRL, 0xf, 0xf, true);
  unsigned hi = (unsigned)__builtin_amdgcn_update_dpp(
      0, (int)(unsigned)(x>>32), CTRL, 0xf, 0xf, true);
  unsigned long long o = ((unsigned long long)hi<<32) | lo;
  return o > x ? o : x;
}
// full-wave u64 max -> valid in lane 63
static __device__ __forceinline__ unsigned long long wave_max63_u64(unsigned long long x){
  x = dppmax_u64<0x111>(x);
  x = dppmax_u64<0x112>(x);
  x = dppmax_u64<0x114>(x);
  x = dppmax_u64<0x118>(x);
  x = dppmax_u64<0x142>(x);
  x = dppmax_u64<0x143>(x);
  return x;
}
static __device__ __forceinline__ unsigned long long readlane_u64(unsigned long long v, int l){
  unsigned lo = (unsigned)__builtin_amdgcn_readlane((int)(unsigned)v, l);
  unsigned hi = (unsigned)__builtin_amdgcn_readlane((int)(unsigned)(v>>32), l);
  return ((unsigned long long)hi<<32) | lo;
}

// ---------------------------------------------------------------------------
// prep: transpose points (B,CF,N)->(B,N,CF) and compute sq_xyz with rn ops
// ---------------------------------------------------------------------------
__global__ __launch_bounds__(256) void prep_kernel(const float* __restrict__ pts,
    const float* __restrict__ xyz, float* __restrict__ ptsT, float* __restrict__ sqx){
  int blk = blockIdx.x;            // 256 blocks = 16 b * 16 chunks
  int b = blk >> 4;
  int n = ((blk & 15) << 8) + threadIdx.x;
  const float* src = pts + (size_t)b*NCF*NN + n;
  float v[NCF];
  #pragma unroll
  for (int c=0;c<NCF;c++) v[c] = src[(size_t)c*NN];
  float4* dst = (float4*)(ptsT + ((size_t)b*NN + n)*NCF);
  #pragma unroll
  for (int j=0;j<16;j++) dst[j] = make_float4(v[4*j],v[4*j+1],v[4*j+2],v[4*j+3]);
  const float* xp = xyz + ((size_t)b*NN + n)*3;
  float x=xp[0], y=xp[1], z=xp[2];
  sqx[(size_t)b*NN+n] = fadd(fadd(fmul(x,x),fmul(y,y)),fmul(z,z));
}

// ---------------------------------------------------------------------------
// FPS: one block per batch, 256 threads (4 waves), CONTIGUOUS ownership:
// thread t owns points [16t, 16t+16) -> lane order == n order within a wave.
// Per step: packed rn distance update -> per-lane (bv,bj) with strict > ->
// DPP f32 max to lane63 -> readlane -> ballot(bv==max)+ffs -> readlane(n) ->
// per-wave u64 key (f32bits<<32 | ~n) -> 4 leader ds_write_b64 (parity slots)
// -> 1 barrier -> 2x ds_read_b128 + 3 u64 max. np.argmax exact (tie->lowest n).
// ---------------------------------------------------------------------------
#define FT 256
__global__ __launch_bounds__(FT) void fps_kernel(const float* __restrict__ xyz,
    int* __restrict__ fidx, float* __restrict__ newxyz){
  int b = blockIdx.x;
  __shared__ float4 s4[NN];                       // 64 KB packed coords
  __shared__ unsigned long long candK[2][4];      // parity-double-buffered
  const int tid = threadIdx.x;
  for (int i = tid; i < NN; i += FT){
    const float* p = xyz + ((size_t)b*NN + i)*3;
    s4[i] = make_float4(p[0], p[1], p[2], 0.f);
  }
  __syncthreads();
  // pair m: .x -> n = 16*tid + 2m, .y -> n = 16*tid + 2m + 1 (ascending)
  f2 px[8], py[8], pz[8], d2[8];
  #pragma unroll
  for (int m=0;m<8;m++){
    float4 a = s4[tid*16 + 2*m];
    float4 c = s4[tid*16 + 2*m + 1];
    px[m] = (f2){a.x, c.x};
    py[m] = (f2){a.y, c.y};
    pz[m] = (f2){a.z, c.z};
    d2[m] = (f2){1e10f, 1e10f};
  }
  int far = 0;
  float4 cc = s4[0];
  for (int s=0;s<NS;s++){
    if (tid==0){
      fidx[b*NS+s] = far;
      float* o = newxyz + ((size_t)b*NS+s)*3;
      o[0]=cc.x; o[1]=cc.y; o[2]=cc.z;
    }
    f2 ncx = (f2){-cc.x,-cc.x}, ncy = (f2){-cc.y,-cc.y}, ncz = (f2){-cc.z,-cc.z};
    float bv = -1.0f; int bj = 0;
    #pragma unroll
    for (int m=0;m<8;m++){
      f2 dx,dy,dz,xx,yy,zz,ss,dd;
      PK_ADD(dx, px[m], ncx);              // = p - c  (rn sub per element)
      PK_ADD(dy, py[m], ncy);
      PK_ADD(dz, pz[m], ncz);
      PK_MUL(xx, dx, dx);
      PK_MUL(yy, dy, dy);
      PK_ADD(ss, xx, yy);                  // (dx2+dy2)
      PK_MUL(zz, dz, dz);
      PK_ADD(dd, ss, zz);                  // +dz2 — numpy order, rn each
      float u0 = fminf(d2[m].x, dd.x);
      float u1 = fminf(d2[m].y, dd.y);
      d2[m].x = u0; d2[m].y = u1;
      if (u0 > bv){ bv = u0; bj = 2*m; }   // strict >: keeps lowest local n
      if (u1 > bv){ bv = u1; bj = 2*m+1; }
    }
    int nbest = (tid<<4) + bj;             // global n of this lane's winner
    // intra-wave: DPP max of bv -> lane 63 -> broadcast via readlane
    float mv = wave_max63_f32(bv);
    float mvu = __uint_as_float((unsigned)__builtin_amdgcn_readlane(
        (int)__float_as_uint(mv), 63));
    unsigned long long tiedm = __ballot(bv == mvu);
    int wl = __ffsll(tiedm) - 1;           // lowest lane = lowest n (contiguous map)
    unsigned nwin = (unsigned)__builtin_amdgcn_readlane(nbest, wl);
    if ((tid & 63) == 0)
      candK[s&1][tid>>6] = ((unsigned long long)__float_as_uint(mvu) << 32)
                         | (unsigned long long)(unsigned)~nwin;
    __syncthreads();
    const ulonglong2* cp = (const ulonglong2*)candK[s&1];
    ulonglong2 c0 = cp[0], c1 = cp[1];
    unsigned long long kk = umax64(umax64(c0.x,c0.y), umax64(c1.x,c1.y));
    far = (int)(~(unsigned)kk) & (NN-1);
    cc = s4[far];
  }
}

__global__ __launch_bounds__(256) void dcen_kernel(const float* __restrict__ density,
    const int* __restrict__ fidx, float* __restrict__ dcen){
  int i = blockIdx.x*256 + threadIdx.x;   // 16384
  int b = i >> 10;
  dcen[i] = density[(size_t)b*NN + fidx[i]];
}

__global__ __launch_bounds__(256) void dstats_kernel(const float* __restrict__ dcen,
    float* __restrict__ dstat){
  float s=0.f, q=0.f;
  for (int i=threadIdx.x; i<NB*NS; i+=256){ float v=dcen[i]; s+=v; q+=v*v; }
  __shared__ float ls[256], lq[256];
  ls[threadIdx.x]=s; lq[threadIdx.x]=q;
  __syncthreads();
  for (int off=128; off>0; off>>=1){
    if (threadIdx.x<off){ ls[threadIdx.x]+=ls[threadIdx.x+off]; lq[threadIdx.x]+=lq[threadIdx.x+off]; }
    __syncthreads();
  }
  if (threadIdx.x==0){
    float m = ls[0]/(float)(NB*NS);
    dstat[0]=m; dstat[1]=lq[0]/(float)(NB*NS) - m*m;
  }
}

// ---------------------------------------------------------------------------
// kNN: one wave per center; wave-held top-32 in lanes 0..31 (empty = ~0ULL,
// lanes 32..63 hold 0). Key = sortable(d)<<32 | n -> exact (d, n) lex order.
// Insertion: broadcast via dynamic readlane; worst via 6-stage DPP u64 max
// (pure VALU) + 2 readlanes; worstLane via ballot. Neighbor ORDER irrelevant
// downstream (perm-invariant MLP+max), only the SET matters.
// ---------------------------------------------------------------------------
__global__ __launch_bounds__(256) void knn_kernel(const float* __restrict__ xyz,
    const float* __restrict__ sqx, const float* __restrict__ newxyz,
    int* __restrict__ kidx){
  const int lane = threadIdx.x & 63;
  const int g = blockIdx.x*4 + (threadIdx.x >> 6);
  const int b = g >> 10;
  const float* cp = newxyz + (size_t)g*3;
  const float cx=cp[0], cy=cp[1], cz=cp[2];
  const float sqc = fadd(fadd(fmul(cx,cx),fmul(cy,cy)),fmul(cz,cz));
  const float* xb  = xyz + (size_t)b*NN*3;
  const float* sqb = sqx + (size_t)b*NN;
  unsigned long long kept  = (lane < 32) ? ~0ULL : 0ULL;
  unsigned long long worst = ~0ULL;
  int worstLane = 0;
  for (int n0=0; n0<NN; n0+=64){
    const int n = n0 + lane;
    const float* xp = xb + (size_t)n*3;
    float x=xp[0], y=xp[1], z=xp[2];
    float dot = fadd(fadd(fmul(cx,x),fmul(cy,y)),fmul(cz,z));
    float d = fsub(fadd(sqc, sqb[n]), fmul(2.0f,dot));
    unsigned u = __float_as_uint(d);
    u = (u & 0x80000000u) ? ~u : (u | 0x80000000u);   // total order incl. negatives
    unsigned long long ck = ((unsigned long long)u << 32) | (unsigned)n;
    unsigned long long mask = __ballot(ck < worst);
    while (mask){
      const int l = __ffsll((unsigned long long)mask) - 1;
      mask &= mask - 1;
      const unsigned long long k = readlane_u64(ck, l);
      if (k < worst){                       // uniform across wave
        if (lane == worstLane) kept = k;
        unsigned long long w = wave_max63_u64(kept);
        worst = readlane_u64(w, 63);
        unsigned long long mm = __ballot(kept == worst);
        worstLane = __ffsll(mm) - 1;
      }
    }
  }
  if (lane < 32) kidx[(size_t)g*NK + lane] = (int)(kept & 0xFFFFFFFFULL);
}

// ---------------------------------------------------------------------------
// conv1: block=256, 128 pts, 2pts x 16outs per thread. DPP sum tails.
// ---------------------------------------------------------------------------
__global__ __launch_bounds__(256) void conv1_kernel(const float* __restrict__ xyz,
    const float* __restrict__ ptsT, const float* __restrict__ newxyz,
    const int* __restrict__ kidx, const float* __restrict__ w0,
    const float* __restrict__ b0, unsigned short* __restrict__ z1,
    float* __restrict__ partial){
  __shared__ float si[CIN][128];
  __shared__ float sw[CIN][64];
  __shared__ float sbias[64];
  const int tid = threadIdx.x;
  for (int i = tid; i < CIN*64; i += 256){
    int o = i / CIN, c = i - o*CIN;
    sw[c][o] = w0[i];
  }
  if (tid < 64) sbias[tid] = b0[tid];
  const int p0 = blockIdx.x * 128;
  if (tid < 128){
    const int p = p0 + tid;
    const int g = p >> 5;
    const int b = g >> 10;
    const int n = kidx[p];
    const float* xp = xyz + ((size_t)b*NN + n)*3;
    const float* cp = newxyz + (size_t)g*3;
    si[0][tid] = xp[0]-cp[0];
    si[1][tid] = xp[1]-cp[1];
    si[2][tid] = xp[2]-cp[2];
    const float4* pr = (const float4*)(ptsT + ((size_t)b*NN + n)*NCF);
    #pragma unroll
    for (int j=0;j<16;j++){
      float4 v = pr[j];
      si[3+4*j][tid]=v.x; si[4+4*j][tid]=v.y; si[5+4*j][tid]=v.z; si[6+4*j][tid]=v.w;
    }
  }
  __syncthreads();
  const int og = tid >> 6;     // wave id, 16 outputs
  const int pg = tid & 63;     // 2 points
  float acc0[16], acc1[16];
  #pragma unroll
  for (int j=0;j<16;j++){ float bv = sbias[og*16+j]; acc0[j]=bv; acc1[j]=bv; }
  for (int c=0;c<CIN;c++){
    float2 a = *(const float2*)&si[c][2*pg];
    const float4* wr = (const float4*)&sw[c][og*16];
    #pragma unroll
    for (int q=0;q<4;q++){
      float4 w = wr[q];
      acc0[4*q+0]+=a.x*w.x; acc0[4*q+1]+=a.x*w.y; acc0[4*q+2]+=a.x*w.z; acc0[4*q+3]+=a.x*w.w;
      acc1[4*q+0]+=a.y*w.x; acc1[4*q+1]+=a.y*w.y; acc1[4*q+2]+=a.y*w.z; acc1[4*q+3]+=a.y*w.w;
    }
  }
  unsigned v[8];
  #pragma unroll
  for (int j=0;j<8;j++) v[j] = (unsigned)f2b(acc0[2*j]) | ((unsigned)f2b(acc0[2*j+1])<<16);
  uint4* d0 = (uint4*)(z1 + (size_t)(p0+2*pg)*64 + og*16);
  d0[0]=make_uint4(v[0],v[1],v[2],v[3]); d0[1]=make_uint4(v[4],v[5],v[6],v[7]);
  #pragma unroll
  for (int j=0;j<8;j++) v[j] = (unsigned)f2b(acc1[2*j]) | ((unsigned)f2b(acc1[2*j+1])<<16);
  uint4* d1 = (uint4*)(z1 + (size_t)(p0+2*pg+1)*64 + og*16);
  d1[0]=make_uint4(v[0],v[1],v[2],v[3]); d1[1]=make_uint4(v[4],v[5],v[6],v[7]);
  #pragma unroll
  for (int j=0;j<16;j++){
    float s = wave_sum63_f32(acc0[j]+acc1[j]);
    float q = wave_sum63_f32(acc0[j]*acc0[j] + acc1[j]*acc1[j]);
    if (pg==63){
      partial[(size_t)blockIdx.x*128 + og*16 + j] = s;
      partial[(size_t)blockIdx.x*128 + 64 + og*16 + j] = q;
    }
  }
}

__global__ __launch_bounds__(256) void conv2_kernel(const unsigned short* __restrict__ z1,
    const float* __restrict__ w1, const float* __restrict__ b1,
    const float* __restrict__ scale1, const float* __restrict__ shift1,
    unsigned short* __restrict__ z2, float* __restrict__ partial){
  __shared__ float si[64][128];
  __shared__ float sw[64][64];
  __shared__ float sbias[64];
  const int tid = threadIdx.x;
  for (int i = tid; i < 64*64; i += 256){
    int o = i >> 6, c = i & 63;
    sw[c][o] = w1[i];
  }
  if (tid < 64) sbias[tid] = b1[tid];
  const int p0 = blockIdx.x * 128;
  if (tid < 128){
    const uint4* zr = (const uint4*)(z1 + (size_t)(p0 + tid)*64);
    #pragma unroll
    for (int j=0;j<8;j++){
      uint4 vv = zr[j];
      unsigned a[4] = {vv.x, vv.y, vv.z, vv.w};
      #pragma unroll
      for (int t=0;t<4;t++){
        int c = j*8 + t*2;
        float lo = __uint_as_float(a[t] << 16);
        float hi = __uint_as_float(a[t] & 0xFFFF0000u);
        si[c][tid]   = fmaxf(lo*scale1[c]   + shift1[c],   0.0f);
        si[c+1][tid] = fmaxf(hi*scale1[c+1] + shift1[c+1], 0.0f);
      }
    }
  }
  __syncthreads();
  const int og = tid >> 6;
  const int pg = tid & 63;
  float acc0[16], acc1[16];
  #pragma unroll
  for (int j=0;j<16;j++){ float bv = sbias[og*16+j]; acc0[j]=bv; acc1[j]=bv; }
  for (int c=0;c<64;c++){
    float2 a = *(const float2*)&si[c][2*pg];
    const float4* wr = (const float4*)&sw[c][og*16];
    #pragma unroll
    for (int q=0;q<4;q++){
      float4 w = wr[q];
      acc0[4*q+0]+=a.x*w.x; acc0[4*q+1]+=a.x*w.y; acc0[4*q+2]+=a.x*w.z; acc0[4*q+3]+=a.x*w.w;
      acc1[4*q+0]+=a.y*w.x; acc1[4*q+1]+=a.y*w.y; acc1[4*q+2]+=a.y*w.z; acc1[4*q+3]+=a.y*w.w;
    }
  }
  unsigned v[8];
  #pragma unroll
  for (int j=0;j<8;j++) v[j] = (unsigned)f2b(acc0[2*j]) | ((unsigned)f2b(acc0[2*j+1])<<16);
  uint4* d0 = (uint4*)(z2 + (size_t)(p0+2*pg)*64 + og*16);
  d0[0]=make_uint4(v[0],v[1],v[2],v[3]); d0[1]=make_uint4(v[4],v[5],v[6],v[7]);
  #pragma unroll
  for (int j=0;j<8;j++) v[j] = (unsigned)f2b(acc1[2*j]) | ((unsigned)f2b(acc1[2*j+1])<<16);
  uint4* d1 = (uint4*)(z2 + (size_t)(p0+2*pg+1)*64 + og*16);
  d1[0]=make_uint4(v[0],v[1],v[2],v[3]); d1[1]=make_uint4(v[4],v[5],v[6],v[7]);
  #pragma unroll
  for (int j=0;j<16;j++){
    float s = wave_sum63_f32(acc0[j]+acc1[j]);
    float q = wave_sum63_f32(acc0[j]*acc0[j] + acc1[j]*acc1[j]);
    if (pg==63){
      partial[(size_t)blockIdx.x*128 + og*16 + j] = s;
      partial[(size_t)blockIdx.x*128 + 64 + og*16 + j] = q;
    }
  }
}

// conv3: 128 pts (4 centers)/block, 4pts x 16outs per thread. DPP tails.
// Max over k fused pre-BN (BN3 scale>0, density weight>=0).
__global__ __launch_bounds__(256) void conv3_kernel(const unsigned short* __restrict__ z2,
    const float* __restrict__ w2, const float* __restrict__ b2,
    const float* __restrict__ scale2, const float* __restrict__ shift2,
    float* __restrict__ m3, float* __restrict__ partial){
  __shared__ float si[64][128];
  __shared__ float sw[64][128];
  const int tid = threadIdx.x;
  for (int i = tid; i < 64*128; i += 256){
    int o = i >> 6, c = i & 63;
    sw[c][o] = w2[i];
  }
  const int p0 = blockIdx.x * 128;     // grid 4096
  if (tid < 128){
    const uint4* zr = (const uint4*)(z2 + (size_t)(p0 + tid)*64);
    #pragma unroll
    for (int j=0;j<8;j++){
      uint4 vv = zr[j];
      unsigned a[4]={vv.x,vv.y,vv.z,vv.w};
      #pragma unroll
      for (int t=0;t<4;t++){
        int c = j*8+t*2;
        float lo=__uint_as_float(a[t]<<16), hi=__uint_as_float(a[t]&0xFFFF0000u);
        si[c][tid]   = fmaxf(lo*scale2[c]+shift2[c],0.f);
        si[c+1][tid] = fmaxf(hi*scale2[c+1]+shift2[c+1],0.f);
      }
    }
  }
  __syncthreads();
  const int og = tid >> 5;    // 0..7 -> outputs og*16..+15
  const int pg = tid & 31;    // 4 pts: p0 + pg*4 .. +3 (center = pg>>3)
  float acc[4][16];
  const float4* bq = (const float4*)(b2 + og*16);
  #pragma unroll
  for (int q=0;q<4;q++){
    float4 bb = bq[q];
    #pragma unroll
    for (int p=0;p<4;p++){ acc[p][4*q]=bb.x; acc[p][4*q+1]=bb.y; acc[p][4*q+2]=bb.z; acc[p][4*q+3]=bb.w; }
  }
  for (int c=0;c<64;c++){
    float4 a = *(const float4*)&si[c][pg*4];
    const float4* wr = (const float4*)&sw[c][og*16];
    float ap[4] = {a.x, a.y, a.z, a.w};
    #pragma unroll
    for (int q=0;q<4;q++){
      float4 w = wr[q];
      #pragma unroll
      for (int p=0;p<4;p++){
        acc[p][4*q+0]+=ap[p]*w.x; acc[p][4*q+1]+=ap[p]*w.y;
        acc[p][4*q+2]+=ap[p]*w.z; acc[p][4*q+3]+=ap[p]*w.w;
      }
    }
  }
  float mx[16];
  #pragma unroll
  for (int j=0;j<16;j++){
    float m = fmaxf(fmaxf(acc[0][j],acc[1][j]), fmaxf(acc[2][j],acc[3][j]));
    mx[j] = group8_max_f32(m);   // 8-lane group = 1 center; valid in all 8
  }
  if ((pg & 7)==0){
    const int center = blockIdx.x*4 + (pg>>3);
    float4* mp = (float4*)(m3 + (size_t)center*128 + og*16);
    #pragma unroll
    for (int q=0;q<4;q++) mp[q] = make_float4(mx[4*q],mx[4*q+1],mx[4*q+2],mx[4*q+3]);
  }
  #pragma unroll
  for (int j=0;j<16;j++){
    float s = half_sum31_f32(acc[0][j]+acc[1][j]+acc[2][j]+acc[3][j]);
    float q = half_sum31_f32(acc[0][j]*acc[0][j]+acc[1][j]*acc[1][j]
                            +acc[2][j]*acc[2][j]+acc[3][j]*acc[3][j]);
    if (pg==31){
      partial[(size_t)blockIdx.x*256 + og*16 + j] = s;
      partial[(size_t)blockIdx.x*256 + 128 + og*16 + j] = q;
    }
  }
}

// reduce per-block partials -> BN scale/shift per channel (one block per channel)
__global__ __launch_bounds__(256) void mkbn_kernel(const float* __restrict__ partial,
    int nrows, int stride, const float* __restrict__ g, const float* __restrict__ be,
    float* __restrict__ scale, float* __restrict__ shift, float inv_count){
  const int c = blockIdx.x;
  const int C = gridDim.x;
  float s=0.f, q=0.f;
  for (int r=threadIdx.x; r<nrows; r+=256){
    s += partial[(size_t)r*stride + c];
    q += partial[(size_t)r*stride + C + c];
  }
  __shared__ float ls[256], lq[256];
  ls[threadIdx.x]=s; lq[threadIdx.x]=q;
  __syncthreads();
  for (int off=128; off>0; off>>=1){
    if (threadIdx.x < off){ ls[threadIdx.x]+=ls[threadIdx.x+off]; lq[threadIdx.x]+=lq[threadIdx.x+off]; }
    __syncthreads();
  }
  if (threadIdx.x==0){
    float mean = ls[0]*inv_count;
    float var  = lq[0]*inv_count - mean*mean;
    float sc = g[c]*rsqrtf(var + EPSV);
    scale[c]=sc; shift[c]=be[c]-mean*sc;
  }
}

// out[b,ch,s] = relu(scale3*maxz + shift3) * relu(bn_d(wd*dcen+bd))
__global__ __launch_bounds__(256) void final_kernel(const float* __restrict__ m3,
    const float* __restrict__ dcen, const float* __restrict__ scale3,
    const float* __restrict__ shift3, const float* __restrict__ wd,
    const float* __restrict__ bd, const float* __restrict__ gd,
    const float* __restrict__ bed, const float* __restrict__ dstat,
    float* __restrict__ out){
  size_t i = (size_t)blockIdx.x*256 + threadIdx.x;   // 2,097,152 = b*2^17 + ch*2^10 + s
  int s  = (int)(i & 1023);
  int ch = (int)((i >> 10) & 127);
  int b  = (int)(i >> 17);
  float mean_d = dstat[0], var_d = dstat[1];
  float w = wd[ch];
  float meanp = w*mean_d + bd[ch];
  float varp  = w*w*var_d;          // var of affine(dcen): exact algebraic identity
  float dsc = gd[ch]*rsqrtf(varp + EPSV);
  float dsh = bed[ch] - meanp*dsc;
  float pre = w*dcen[b*NS+s] + bd[ch];
  float dw  = fmaxf(dsc*pre + dsh, 0.0f);
  float z   = m3[((size_t)(b*NS+s))*128 + ch];
  float x   = fmaxf(scale3[ch]*z + shift3[ch], 0.0f);
  out[i] = x*dw;
}

// ---------------------------------------------------------------------------
extern "C" void kernel_launch(void* const* d_in, const int* in_sizes, int n_in,
                              void* d_out, int out_size, void* d_ws, size_t ws_size,
                              hipStream_t stream){
  const float* xyz     = (const float*)d_in[0];
  const float* points  = (const float*)d_in[1];
  const float* density = (const float*)d_in[2];
  const float* w0 = (const float*)d_in[3];
  const float* b0 = (const float*)d_in[4];
  const float* g0 = (const float*)d_in[5];
  const float* be0= (const float*)d_in[6];
  const float* w1 = (const float*)d_in[7];
  const float* b1 = (const float*)d_in[8];
  const float* g1 = (const float*)d_in[9];
  const float* be1= (const float*)d_in[10];
  const float* w2 = (const float*)d_in[11];
  const float* b2 = (const float*)d_in[12];
  const float* g2 = (const float*)d_in[13];
  const float* be2= (const float*)d_in[14];
  const float* wd = (const float*)d_in[15];
  const float* bd = (const float*)d_in[16];
  const float* gd = (const float*)d_in[17];
  const float* bed= (const float*)d_in[18];

  float* out = (float*)d_out;
  float* newxyz = out;                 // (B,S,3) = output 0
  float* out1   = out + (size_t)NB*NS*3;

  // workspace layout (~174 MB total)
  float* ptsT = (float*)d_ws;                            // 4,194,304 f
  float* sqx  = ptsT + (size_t)NB*NN*NCF;                // 65,536 f
  int*   fidx = (int*)(sqx + (size_t)NB*NN);             // 16,384 i
  float* dcen = (float*)(fidx + NB*NS);                  // 16,384 f
  int*   kidx = (int*)(dcen + NB*NS);                    // 524,288 i
  unsigned short* z1 = (unsigned short*)(kidx + NPTS);   // 33,554,432 us
  unsigned short* z2 = z1 + (size_t)NPTS*64;             // 33,554,432 us
  float* m3   = (float*)(z2 + (size_t)NPTS*64);          // 2,097,152 f
  float* p1   = m3 + (size_t)NB*NS*128;                  // 4096*128 f
  float* p2   = p1 + 4096*128;                           // 4096*128 f
  float* p3   = p2 + 4096*128;                           // 4096*256 f
  float* bnp  = p3 + 4096*256;                           // 512 f (scale/shift x3)
  float* dstat= bnp + 512;                               // 2 f

  hipLaunchKernelGGL(prep_kernel,  dim3(256),  dim3(256), 0, stream, points, xyz, ptsT, sqx);
  hipLaunchKernelGGL(fps_kernel,   dim3(NB),   dim3(FT),  0, stream, xyz, fidx, newxyz);
  hipLaunchKernelGGL(dcen_kernel,  dim3(64),   dim3(256), 0, stream, density, fidx, dcen);
  hipLaunchKernelGGL(dstats_kernel,dim3(1),    dim3(256), 0, stream, dcen, dstat);
  hipLaunchKernelGGL(knn_kernel,   dim3(4096), dim3(256), 0, stream, xyz, sqx, newxyz, kidx);
  hipLaunchKernelGGL(conv1_kernel, dim3(4096), dim3(256), 0, stream, xyz, ptsT, newxyz, kidx, w0, b0, z1, p1);
  hipLaunchKernelGGL(mkbn_kernel,  dim3(64),   dim3(256), 0, stream, p1, 4096, 128, g0, be0, bnp+0,   bnp+64,  1.0f/(float)NPTS);
  hipLaunchKernelGGL(conv2_kernel, dim3(4096), dim3(256), 0, stream, z1, w1, b1, bnp+0, bnp+64, z2, p2);
  hipLaunchKernelGGL(mkbn_kernel,  dim3(64),   dim3(256), 0, stream, p2, 4096, 128, g1, be1, bnp+128, bnp+192, 1.0f/(float)NPTS);
  hipLaunchKernelGGL(conv3_kernel, dim3(4096), dim3(256), 0, stream, z2, w2, b2, bnp+128, bnp+192, m3, p3);
  hipLaunchKernelGGL(mkbn_kernel,  dim3(128),  dim3(256), 0, stream, p3, 4096, 256, g2, be2, bnp+256, bnp+384, 1.0f/(float)NPTS);
  hipLaunchKernelGGL(final_kernel, dim3(8192), dim3(256), 0, stream, m3, dcen, bnp+256, bnp+384, wd, bd, gd, bed, dstat, out1);
}

// Round 5
// 1330.966 us; speedup vs baseline: 2.0099x; 1.0586x over previous
//
#include <hip/hip_runtime.h>
#include <hip/hip_bf16.h>
#include <stdint.h>

// Problem constants (fixed by the reference)
#define NB 16
#define NN 4096
#define NCF 64
#define NS 1024
#define NK 32
#define NPTS (NB*NS*NK)   // 524288
#define CIN 67
#define EPSV 1e-5f

// rn intrinsics: block FMA contraction so FPS/kNN distances bit-match numpy
static __device__ __forceinline__ float fmul(float a, float b){ return __fmul_rn(a,b); }
static __device__ __forceinline__ float fadd(float a, float b){ return __fadd_rn(a,b); }
static __device__ __forceinline__ float fsub(float a, float b){ return __fsub_rn(a,b); }

typedef float f2 __attribute__((ext_vector_type(2)));
// Packed f32 ops (VOP3P): per-element rn add/mul, identical semantics to
// scalar v_add_f32/v_mul_f32 — safe for the exact-index FPS recipe.
#define PK_ADD(d,a,b) asm("v_pk_add_f32 %0, %1, %2" : "=v"(d) : "v"(a), "v"(b))
#define PK_MUL(d,a,b) asm("v_pk_mul_f32 %0, %1, %2" : "=v"(d) : "v"(a), "v"(b))

static __device__ __forceinline__ unsigned short f2b(float f){
  unsigned u = __float_as_uint(f);
  return (unsigned short)((u + 0x7FFFu + ((u>>16)&1u)) >> 16);  // RNE bf16
}

// ---- DPP cross-lane reductions (pure VALU — no LDS latency) ----------------
template<int CTRL>
static __device__ __forceinline__ float dppmax_f32(float x){
  float o = __uint_as_float((unsigned)__builtin_amdgcn_update_dpp(
      0, (int)__float_as_uint(x), CTRL, 0xf, 0xf, true));
  return fmaxf(x, o);
}
// full-wave max -> valid in lane 63
static __device__ __forceinline__ float wave_max63_f32(float x){
  x = dppmax_f32<0x111>(x);  // row_shr:1
  x = dppmax_f32<0x112>(x);  // row_shr:2
  x = dppmax_f32<0x114>(x);  // row_shr:4
  x = dppmax_f32<0x118>(x);  // row_shr:8
  x = dppmax_f32<0x142>(x);  // row_bcast:15
  x = dppmax_f32<0x143>(x);  // row_bcast:31
  return x;
}
template<int CTRL>
static __device__ __forceinline__ float dppadd_f32(float x){
  float o = __uint_as_float((unsigned)__builtin_amdgcn_update_dpp(
      0, (int)__float_as_uint(x), CTRL, 0xf, 0xf, true));
  return x + o;
}
// full-wave sum -> valid in lane 63
static __device__ __forceinline__ float wave_sum63_f32(float x){
  x = dppadd_f32<0x111>(x);
  x = dppadd_f32<0x112>(x);
  x = dppadd_f32<0x114>(x);
  x = dppadd_f32<0x118>(x);
  x = dppadd_f32<0x142>(x);
  x = dppadd_f32<0x143>(x);
  return x;
}
// 32-half sum -> valid in lanes 31 and 63
static __device__ __forceinline__ float half_sum31_f32(float x){
  x = dppadd_f32<0x111>(x);
  x = dppadd_f32<0x112>(x);
  x = dppadd_f32<0x114>(x);
  x = dppadd_f32<0x118>(x);
  x = dppadd_f32<0x142>(x);  // row_bcast:15 -> lane31/63 hold 32-half totals
  return x;
}
// 8-lane-group max, result in ALL 8 lanes (quad_perm xor1, xor2, half_mirror)
static __device__ __forceinline__ float group8_max_f32(float x){
  x = dppmax_f32<0xB1>(x);   // quad_perm [1,0,3,2]
  x = dppmax_f32<0x4E>(x);   // quad_perm [2,3,0,1]
  x = dppmax_f32<0x141>(x);  // row_half_mirror
  return x;
}
static __device__ __forceinline__ unsigned long long readlane_u64(unsigned long long v, int l){
  unsigned lo = (unsigned)__builtin_amdgcn_readlane((int)(unsigned)v, l);
  unsigned hi = (unsigned)__builtin_amdgcn_readlane((int)(unsigned)(v>>32), l);
  return ((unsigned long long)hi<<32) | lo;
}
// whole-wave shift toward higher lanes by 1 (DPP wave_shr:1); lane0 <- 0
static __device__ __forceinline__ unsigned long long wave_shr1_u64(unsigned long long x){
  unsigned lo = (unsigned)__builtin_amdgcn_update_dpp(
      0, (int)(unsigned)x, 0x138, 0xf, 0xf, true);
  unsigned hi = (unsigned)__builtin_amdgcn_update_dpp(
      0, (int)(unsigned)(x>>32), 0x138, 0xf, 0xf, true);
  return ((unsigned long long)hi<<32) | lo;
}

// ---------------------------------------------------------------------------
// prep: transpose points (B,CF,N)->(B,N,CF) and compute sq_xyz with rn ops
// ---------------------------------------------------------------------------
__global__ __launch_bounds__(256) void prep_kernel(const float* __restrict__ pts,
    const float* __restrict__ xyz, float* __restrict__ ptsT, float* __restrict__ sqx){
  int blk = blockIdx.x;            // 256 blocks = 16 b * 16 chunks
  int b = blk >> 4;
  int n = ((blk & 15) << 8) + threadIdx.x;
  const float* src = pts + (size_t)b*NCF*NN + n;
  float v[NCF];
  #pragma unroll
  for (int c=0;c<NCF;c++) v[c] = src[(size_t)c*NN];
  float4* dst = (float4*)(ptsT + ((size_t)b*NN + n)*NCF);
  #pragma unroll
  for (int j=0;j<16;j++) dst[j] = make_float4(v[4*j],v[4*j+1],v[4*j+2],v[4*j+3]);
  const float* xp = xyz + ((size_t)b*NN + n)*3;
  float x=xp[0], y=xp[1], z=xp[2];
  sqx[(size_t)b*NN+n] = fadd(fadd(fmul(x,x),fmul(y,y)),fmul(z,z));
}

// ---------------------------------------------------------------------------
// FPS: one block per batch, 256 threads (4 waves), CONTIGUOUS ownership:
// thread t owns points [16t, 16t+16) -> lane order == n order within a wave.
// Per step: packed rn distance update -> per-lane (bv,bj) strict > ->
// DPP f32 max -> readlane(63) -> ballot tie -> winner lane reads s4[nwin]
// BEFORE the barrier (latency overlaps barrier) and writes {key, coords} to
// its wave slot -> 1 barrier -> all threads read 4 keys + 4 coord vecs in one
// go, select max key + matching coords via cndmask. No post-barrier dependent
// LDS read. np.argmax exact (max value, tie -> lowest index).
// ---------------------------------------------------------------------------
#define FT 256
__global__ __launch_bounds__(FT) void fps_kernel(const float* __restrict__ xyz,
    int* __restrict__ fidx, float* __restrict__ newxyz){
  int b = blockIdx.x;
  __shared__ float4 s4[NN];                       // 64 KB packed coords
  __shared__ unsigned long long candK[2][4];      // parity-double-buffered keys
  __shared__ float4 candC[2][4];                  // winner coords per wave
  const int tid = threadIdx.x;
  const int lane = tid & 63;
  const int wv = tid >> 6;
  for (int i = tid; i < NN; i += FT){
    const float* p = xyz + ((size_t)b*NN + i)*3;
    s4[i] = make_float4(p[0], p[1], p[2], 0.f);
  }
  __syncthreads();
  // pair m: .x -> n = 16*tid + 2m, .y -> n = 16*tid + 2m + 1 (ascending)
  f2 px[8], py[8], pz[8], d2[8];
  #pragma unroll
  for (int m=0;m<8;m++){
    float4 a = s4[tid*16 + 2*m];
    float4 c = s4[tid*16 + 2*m + 1];
    px[m] = (f2){a.x, c.x};
    py[m] = (f2){a.y, c.y};
    pz[m] = (f2){a.z, c.z};
    d2[m] = (f2){1e10f, 1e10f};
  }
  int far = 0;
  float4 cc = s4[0];
  for (int s=0;s<NS;s++){
    if (tid==0){
      fidx[b*NS+s] = far;
      float* o = newxyz + ((size_t)b*NS+s)*3;
      o[0]=cc.x; o[1]=cc.y; o[2]=cc.z;
    }
    f2 ncx = (f2){-cc.x,-cc.x}, ncy = (f2){-cc.y,-cc.y}, ncz = (f2){-cc.z,-cc.z};
    float bv = -1.0f; int bj = 0;
    #pragma unroll
    for (int m=0;m<8;m++){
      f2 dx,dy,dz,xx,yy,zz,ss,dd;
      PK_ADD(dx, px[m], ncx);              // = p - c  (rn sub per element)
      PK_ADD(dy, py[m], ncy);
      PK_ADD(dz, pz[m], ncz);
      PK_MUL(xx, dx, dx);
      PK_MUL(yy, dy, dy);
      PK_ADD(ss, xx, yy);                  // (dx2+dy2)
      PK_MUL(zz, dz, dz);
      PK_ADD(dd, ss, zz);                  // +dz2 — numpy order, rn each
      float u0 = fminf(d2[m].x, dd.x);
      float u1 = fminf(d2[m].y, dd.y);
      d2[m].x = u0; d2[m].y = u1;
      if (u0 > bv){ bv = u0; bj = 2*m; }   // strict >: keeps lowest local n
      if (u1 > bv){ bv = u1; bj = 2*m+1; }
    }
    int nbest = (tid<<4) + bj;             // global n of this lane's winner
    float mv = wave_max63_f32(bv);
    float mvu = __uint_as_float((unsigned)__builtin_amdgcn_readlane(
        (int)__float_as_uint(mv), 63));
    unsigned long long tiedm = __ballot(bv == mvu);
    int wl = __ffsll(tiedm) - 1;           // lowest lane = lowest n (contiguous map)
    unsigned nwin = (unsigned)__builtin_amdgcn_readlane(nbest, wl);
    if (lane == wl){
      float4 cw = s4[nwin];                // latency overlaps barrier arrival
      candK[s&1][wv] = ((unsigned long long)__float_as_uint(mvu) << 32)
                     | (unsigned long long)(unsigned)~nwin;
      candC[s&1][wv] = cw;
    }
    __syncthreads();
    const ulonglong2* kp = (const ulonglong2*)candK[s&1];
    ulonglong2 k01v = kp[0], k23v = kp[1];
    float4 C0 = candC[s&1][0], C1 = candC[s&1][1];
    float4 C2 = candC[s&1][2], C3 = candC[s&1][3];
    bool a01 = k01v.y > k01v.x;
    unsigned long long k01 = a01 ? k01v.y : k01v.x;
    float4 c01; c01.x = a01?C1.x:C0.x; c01.y = a01?C1.y:C0.y; c01.z = a01?C1.z:C0.z;
    bool a23 = k23v.y > k23v.x;
    unsigned long long k23 = a23 ? k23v.y : k23v.x;
    float4 c23; c23.x = a23?C3.x:C2.x; c23.y = a23?C3.y:C2.y; c23.z = a23?C3.z:C2.z;
    bool af = k23 > k01;
    unsigned long long kk = af ? k23 : k01;
    cc.x = af?c23.x:c01.x; cc.y = af?c23.y:c01.y; cc.z = af?c23.z:c01.z;
    far = (int)(~(unsigned)kk) & (NN-1);
  }
}

__global__ __launch_bounds__(256) void dcen_kernel(const float* __restrict__ density,
    const int* __restrict__ fidx, float* __restrict__ dcen){
  int i = blockIdx.x*256 + threadIdx.x;   // 16384
  int b = i >> 10;
  dcen[i] = density[(size_t)b*NN + fidx[i]];
}

__global__ __launch_bounds__(256) void dstats_kernel(const float* __restrict__ dcen,
    float* __restrict__ dstat){
  float s=0.f, q=0.f;
  for (int i=threadIdx.x; i<NB*NS; i+=256){ float v=dcen[i]; s+=v; q+=v*v; }
  __shared__ float ls[256], lq[256];
  ls[threadIdx.x]=s; lq[threadIdx.x]=q;
  __syncthreads();
  for (int off=128; off>0; off>>=1){
    if (threadIdx.x<off){ ls[threadIdx.x]+=ls[threadIdx.x+off]; lq[threadIdx.x]+=lq[threadIdx.x+off]; }
    __syncthreads();
  }
  if (threadIdx.x==0){
    float m = ls[0]/(float)(NB*NS);
    dstat[0]=m; dstat[1]=lq[0]/(float)(NB*NS) - m*m;
  }
}

// ---------------------------------------------------------------------------
// kNN: one wave per center; top-32 kept SORTED ASCENDING across lanes 0..31
// (key = sortable(d)<<32 | n -> exact (d,n) lex order; keys unique via n).
// Insertion: v_cmp_gt_u64 + ballot + DPP wave_shr:1 + cndmask + readlane(31)
// -> ~14 VALU vs ~45 for reduce-based replace-worst. Lanes 32..63 hold junk
// shifted past lane 31 (ignored). Neighbor ORDER irrelevant downstream.
// ---------------------------------------------------------------------------
__global__ __launch_bounds__(256) void knn_kernel(const float* __restrict__ xyz,
    const float* __restrict__ sqx, const float* __restrict__ newxyz,
    int* __restrict__ kidx){
  const int lane = threadIdx.x & 63;
  const int g = blockIdx.x*4 + (threadIdx.x >> 6);
  const int b = g >> 10;
  const float* cp = newxyz + (size_t)g*3;
  const float cx=cp[0], cy=cp[1], cz=cp[2];
  const float sqc = fadd(fadd(fmul(cx,cx),fmul(cy,cy)),fmul(cz,cz));
  const float* xb  = xyz + (size_t)b*NN*3;
  const float* sqb = sqx + (size_t)b*NN;
  unsigned long long kept  = ~0ULL;     // all slots empty (= +inf key)
  unsigned long long worst = ~0ULL;     // kept[31]
  for (int n0=0; n0<NN; n0+=64){
    const int n = n0 + lane;
    const float* xp = xb + (size_t)n*3;
    float x=xp[0], y=xp[1], z=xp[2];
    float dot = fadd(fadd(fmul(cx,x),fmul(cy,y)),fmul(cz,z));
    float d = fsub(fadd(sqc, sqb[n]), fmul(2.0f,dot));
    unsigned u = __float_as_uint(d);
    u = (u & 0x80000000u) ? ~u : (u | 0x80000000u);   // total order incl. negatives
    unsigned long long ck = ((unsigned long long)u << 32) | (unsigned)n;
    unsigned long long mask = __ballot(ck < worst);
    while (mask){
      const int l = __ffsll(mask) - 1;
      mask &= mask - 1;
      const unsigned long long k = readlane_u64(ck, l);
      if (k < worst){                     // uniform across wave
        bool m = kept > k;                // lanes >= insertion position
        unsigned long long M = __ballot(m) << 1;
        unsigned long long sh = wave_shr1_u64(kept);
        bool msh = (M >> lane) & 1ULL;    // predecessor also shifted?
        unsigned long long ins = msh ? sh : k;
        kept = m ? ins : kept;
        worst = readlane_u64(kept, 31);
      }
    }
  }
  if (lane < 32) kidx[(size_t)g*NK + lane] = (int)(kept & 0xFFFFFFFFULL);
}

// ---------------------------------------------------------------------------
// conv1: block=256, 128 pts, 2pts x 16outs per thread. DPP sum tails.
// ---------------------------------------------------------------------------
__global__ __launch_bounds__(256) void conv1_kernel(const float* __restrict__ xyz,
    const float* __restrict__ ptsT, const float* __restrict__ newxyz,
    const int* __restrict__ kidx, const float* __restrict__ w0,
    const float* __restrict__ b0, unsigned short* __restrict__ z1,
    float* __restrict__ partial){
  __shared__ float si[CIN][128];
  __shared__ float sw[CIN][64];
  __shared__ float sbias[64];
  const int tid = threadIdx.x;
  for (int i = tid; i < CIN*64; i += 256){
    int o = i / CIN, c = i - o*CIN;
    sw[c][o] = w0[i];
  }
  if (tid < 64) sbias[tid] = b0[tid];
  const int p0 = blockIdx.x * 128;
  if (tid < 128){
    const int p = p0 + tid;
    const int g = p >> 5;
    const int b = g >> 10;
    const int n = kidx[p];
    const float* xp = xyz + ((size_t)b*NN + n)*3;
    const float* cp = newxyz + (size_t)g*3;
    si[0][tid] = xp[0]-cp[0];
    si[1][tid] = xp[1]-cp[1];
    si[2][tid] = xp[2]-cp[2];
    const float4* pr = (const float4*)(ptsT + ((size_t)b*NN + n)*NCF);
    #pragma unroll
    for (int j=0;j<16;j++){
      float4 v = pr[j];
      si[3+4*j][tid]=v.x; si[4+4*j][tid]=v.y; si[5+4*j][tid]=v.z; si[6+4*j][tid]=v.w;
    }
  }
  __syncthreads();
  const int og = tid >> 6;     // wave id, 16 outputs
  const int pg = tid & 63;     // 2 points
  float acc0[16], acc1[16];
  #pragma unroll
  for (int j=0;j<16;j++){ float bv = sbias[og*16+j]; acc0[j]=bv; acc1[j]=bv; }
  for (int c=0;c<CIN;c++){
    float2 a = *(const float2*)&si[c][2*pg];
    const float4* wr = (const float4*)&sw[c][og*16];
    #pragma unroll
    for (int q=0;q<4;q++){
      float4 w = wr[q];
      acc0[4*q+0]+=a.x*w.x; acc0[4*q+1]+=a.x*w.y; acc0[4*q+2]+=a.x*w.z; acc0[4*q+3]+=a.x*w.w;
      acc1[4*q+0]+=a.y*w.x; acc1[4*q+1]+=a.y*w.y; acc1[4*q+2]+=a.y*w.z; acc1[4*q+3]+=a.y*w.w;
    }
  }
  unsigned v[8];
  #pragma unroll
  for (int j=0;j<8;j++) v[j] = (unsigned)f2b(acc0[2*j]) | ((unsigned)f2b(acc0[2*j+1])<<16);
  uint4* d0 = (uint4*)(z1 + (size_t)(p0+2*pg)*64 + og*16);
  d0[0]=make_uint4(v[0],v[1],v[2],v[3]); d0[1]=make_uint4(v[4],v[5],v[6],v[7]);
  #pragma unroll
  for (int j=0;j<8;j++) v[j] = (unsigned)f2b(acc1[2*j]) | ((unsigned)f2b(acc1[2*j+1])<<16);
  uint4* d1 = (uint4*)(z1 + (size_t)(p0+2*pg+1)*64 + og*16);
  d1[0]=make_uint4(v[0],v[1],v[2],v[3]); d1[1]=make_uint4(v[4],v[5],v[6],v[7]);
  #pragma unroll
  for (int j=0;j<16;j++){
    float s = wave_sum63_f32(acc0[j]+acc1[j]);
    float q = wave_sum63_f32(acc0[j]*acc0[j] + acc1[j]*acc1[j]);
    if (pg==63){
      partial[(size_t)blockIdx.x*128 + og*16 + j] = s;
      partial[(size_t)blockIdx.x*128 + 64 + og*16 + j] = q;
    }
  }
}

__global__ __launch_bounds__(256) void conv2_kernel(const unsigned short* __restrict__ z1,
    const float* __restrict__ w1, const float* __restrict__ b1,
    const float* __restrict__ scale1, const float* __restrict__ shift1,
    unsigned short* __restrict__ z2, float* __restrict__ partial){
  __shared__ float si[64][128];
  __shared__ float sw[64][64];
  __shared__ float sbias[64];
  const int tid = threadIdx.x;
  for (int i = tid; i < 64*64; i += 256){
    int o = i >> 6, c = i & 63;
    sw[c][o] = w1[i];
  }
  if (tid < 64) sbias[tid] = b1[tid];
  const int p0 = blockIdx.x * 128;
  if (tid < 128){
    const uint4* zr = (const uint4*)(z1 + (size_t)(p0 + tid)*64);
    #pragma unroll
    for (int j=0;j<8;j++){
      uint4 vv = zr[j];
      unsigned a[4] = {vv.x, vv.y, vv.z, vv.w};
      #pragma unroll
      for (int t=0;t<4;t++){
        int c = j*8 + t*2;
        float lo = __uint_as_float(a[t] << 16);
        float hi = __uint_as_float(a[t] & 0xFFFF0000u);
        si[c][tid]   = fmaxf(lo*scale1[c]   + shift1[c],   0.0f);
        si[c+1][tid] = fmaxf(hi*scale1[c+1] + shift1[c+1], 0.0f);
      }
    }
  }
  __syncthreads();
  const int og = tid >> 6;
  const int pg = tid & 63;
  float acc0[16], acc1[16];
  #pragma unroll
  for (int j=0;j<16;j++){ float bv = sbias[og*16+j]; acc0[j]=bv; acc1[j]=bv; }
  for (int c=0;c<64;c++){
    float2 a = *(const float2*)&si[c][2*pg];
    const float4* wr = (const float4*)&sw[c][og*16];
    #pragma unroll
    for (int q=0;q<4;q++){
      float4 w = wr[q];
      acc0[4*q+0]+=a.x*w.x; acc0[4*q+1]+=a.x*w.y; acc0[4*q+2]+=a.x*w.z; acc0[4*q+3]+=a.x*w.w;
      acc1[4*q+0]+=a.y*w.x; acc1[4*q+1]+=a.y*w.y; acc1[4*q+2]+=a.y*w.z; acc1[4*q+3]+=a.y*w.w;
    }
  }
  unsigned v[8];
  #pragma unroll
  for (int j=0;j<8;j++) v[j] = (unsigned)f2b(acc0[2*j]) | ((unsigned)f2b(acc0[2*j+1])<<16);
  uint4* d0 = (uint4*)(z2 + (size_t)(p0+2*pg)*64 + og*16);
  d0[0]=make_uint4(v[0],v[1],v[2],v[3]); d0[1]=make_uint4(v[4],v[5],v[6],v[7]);
  #pragma unroll
  for (int j=0;j<8;j++) v[j] = (unsigned)f2b(acc1[2*j]) | ((unsigned)f2b(acc1[2*j+1])<<16);
  uint4* d1 = (uint4*)(z2 + (size_t)(p0+2*pg+1)*64 + og*16);
  d1[0]=make_uint4(v[0],v[1],v[2],v[3]); d1[1]=make_uint4(v[4],v[5],v[6],v[7]);
  #pragma unroll
  for (int j=0;j<16;j++){
    float s = wave_sum63_f32(acc0[j]+acc1[j]);
    float q = wave_sum63_f32(acc0[j]*acc0[j] + acc1[j]*acc1[j]);
    if (pg==63){
      partial[(size_t)blockIdx.x*128 + og*16 + j] = s;
      partial[(size_t)blockIdx.x*128 + 64 + og*16 + j] = q;
    }
  }
}

// conv3: 128 pts (4 centers)/block, 4pts x 16outs per thread. DPP tails.
// Max over k fused pre-BN (BN3 scale>0, density weight>=0).
__global__ __launch_bounds__(256) void conv3_kernel(const unsigned short* __restrict__ z2,
    const float* __restrict__ w2, const float* __restrict__ b2,
    const float* __restrict__ scale2, const float* __restrict__ shift2,
    float* __restrict__ m3, float* __restrict__ partial){
  __shared__ float si[64][128];
  __shared__ float sw[64][128];
  const int tid = threadIdx.x;
  for (int i = tid; i < 64*128; i += 256){
    int o = i >> 6, c = i & 63;
    sw[c][o] = w2[i];
  }
  const int p0 = blockIdx.x * 128;     // grid 4096
  if (tid < 128){
    const uint4* zr = (const uint4*)(z2 + (size_t)(p0 + tid)*64);
    #pragma unroll
    for (int j=0;j<8;j++){
      uint4 vv = zr[j];
      unsigned a[4]={vv.x,vv.y,vv.z,vv.w};
      #pragma unroll
      for (int t=0;t<4;t++){
        int c = j*8+t*2;
        float lo=__uint_as_float(a[t]<<16), hi=__uint_as_float(a[t]&0xFFFF0000u);
        si[c][tid]   = fmaxf(lo*scale2[c]+shift2[c],0.f);
        si[c+1][tid] = fmaxf(hi*scale2[c+1]+shift2[c+1],0.f);
      }
    }
  }
  __syncthreads();
  const int og = tid >> 5;    // 0..7 -> outputs og*16..+15
  const int pg = tid & 31;    // 4 pts: p0 + pg*4 .. +3 (center = pg>>3)
  float acc[4][16];
  const float4* bq = (const float4*)(b2 + og*16);
  #pragma unroll
  for (int q=0;q<4;q++){
    float4 bb = bq[q];
    #pragma unroll
    for (int p=0;p<4;p++){ acc[p][4*q]=bb.x; acc[p][4*q+1]=bb.y; acc[p][4*q+2]=bb.z; acc[p][4*q+3]=bb.w; }
  }
  for (int c=0;c<64;c++){
    float4 a = *(const float4*)&si[c][pg*4];
    const float4* wr = (const float4*)&sw[c][og*16];
    float ap[4] = {a.x, a.y, a.z, a.w};
    #pragma unroll
    for (int q=0;q<4;q++){
      float4 w = wr[q];
      #pragma unroll
      for (int p=0;p<4;p++){
        acc[p][4*q+0]+=ap[p]*w.x; acc[p][4*q+1]+=ap[p]*w.y;
        acc[p][4*q+2]+=ap[p]*w.z; acc[p][4*q+3]+=ap[p]*w.w;
      }
    }
  }
  float mx[16];
  #pragma unroll
  for (int j=0;j<16;j++){
    float m = fmaxf(fmaxf(acc[0][j],acc[1][j]), fmaxf(acc[2][j],acc[3][j]));
    mx[j] = group8_max_f32(m);   // 8-lane group = 1 center; valid in all 8
  }
  if ((pg & 7)==0){
    const int center = blockIdx.x*4 + (pg>>3);
    float4* mp = (float4*)(m3 + (size_t)center*128 + og*16);
    #pragma unroll
    for (int q=0;q<4;q++) mp[q] = make_float4(mx[4*q],mx[4*q+1],mx[4*q+2],mx[4*q+3]);
  }
  #pragma unroll
  for (int j=0;j<16;j++){
    float s = half_sum31_f32(acc[0][j]+acc[1][j]+acc[2][j]+acc[3][j]);
    float q = half_sum31_f32(acc[0][j]*acc[0][j]+acc[1][j]*acc[1][j]
                            +acc[2][j]*acc[2][j]+acc[3][j]*acc[3][j]);
    if (pg==31){
      partial[(size_t)blockIdx.x*256 + og*16 + j] = s;
      partial[(size_t)blockIdx.x*256 + 128 + og*16 + j] = q;
    }
  }
}

// reduce per-block partials -> BN scale/shift per channel (one block per channel)
__global__ __launch_bounds__(256) void mkbn_kernel(const float* __restrict__ partial,
    int nrows, int stride, const float* __restrict__ g, const float* __restrict__ be,
    float* __restrict__ scale, float* __restrict__ shift, float inv_count){
  const int c = blockIdx.x;
  const int C = gridDim.x;
  float s=0.f, q=0.f;
  for (int r=threadIdx.x; r<nrows; r+=256){
    s += partial[(size_t)r*stride + c];
    q += partial[(size_t)r*stride + C + c];
  }
  __shared__ float ls[256], lq[256];
  ls[threadIdx.x]=s; lq[threadIdx.x]=q;
  __syncthreads();
  for (int off=128; off>0; off>>=1){
    if (threadIdx.x < off){ ls[threadIdx.x]+=ls[threadIdx.x+off]; lq[threadIdx.x]+=lq[threadIdx.x+off]; }
    __syncthreads();
  }
  if (threadIdx.x==0){
    float mean = ls[0]*inv_count;
    float var  = lq[0]*inv_count - mean*mean;
    float sc = g[c]*rsqrtf(var + EPSV);
    scale[c]=sc; shift[c]=be[c]-mean*sc;
  }
}

// out[b,ch,s] = relu(scale3*maxz + shift3) * relu(bn_d(wd*dcen+bd))
__global__ __launch_bounds__(256) void final_kernel(const float* __restrict__ m3,
    const float* __restrict__ dcen, const float* __restrict__ scale3,
    const float* __restrict__ shift3, const float* __restrict__ wd,
    const float* __restrict__ bd, const float* __restrict__ gd,
    const float* __restrict__ bed, const float* __restrict__ dstat,
    float* __restrict__ out){
  size_t i = (size_t)blockIdx.x*256 + threadIdx.x;   // 2,097,152 = b*2^17 + ch*2^10 + s
  int s  = (int)(i & 1023);
  int ch = (int)((i >> 10) & 127);
  int b  = (int)(i >> 17);
  float mean_d = dstat[0], var_d = dstat[1];
  float w = wd[ch];
  float meanp = w*mean_d + bd[ch];
  float varp  = w*w*var_d;          // var of affine(dcen): exact algebraic identity
  float dsc = gd[ch]*rsqrtf(varp + EPSV);
  float dsh = bed[ch] - meanp*dsc;
  float pre = w*dcen[b*NS+s] + bd[ch];
  float dw  = fmaxf(dsc*pre + dsh, 0.0f);
  float z   = m3[((size_t)(b*NS+s))*128 + ch];
  float x   = fmaxf(scale3[ch]*z + shift3[ch], 0.0f);
  out[i] = x*dw;
}

// ---------------------------------------------------------------------------
extern "C" void kernel_launch(void* const* d_in, const int* in_sizes, int n_in,
                              void* d_out, int out_size, void* d_ws, size_t ws_size,
                              hipStream_t stream){
  const float* xyz     = (const float*)d_in[0];
  const float* points  = (const float*)d_in[1];
  const float* density = (const float*)d_in[2];
  const float* w0 = (const float*)d_in[3];
  const float* b0 = (const float*)d_in[4];
  const float* g0 = (const float*)d_in[5];
  const float* be0= (const float*)d_in[6];
  const float* w1 = (const float*)d_in[7];
  const float* b1 = (const float*)d_in[8];
  const float* g1 = (const float*)d_in[9];
  const float* be1= (const float*)d_in[10];
  const float* w2 = (const float*)d_in[11];
  const float* b2 = (const float*)d_in[12];
  const float* g2 = (const float*)d_in[13];
  const float* be2= (const float*)d_in[14];
  const float* wd = (const float*)d_in[15];
  const float* bd = (const float*)d_in[16];
  const float* gd = (const float*)d_in[17];
  const float* bed= (const float*)d_in[18];

  float* out = (float*)d_out;
  float* newxyz = out;                 // (B,S,3) = output 0
  float* out1   = out + (size_t)NB*NS*3;

  // workspace layout (~174 MB total)
  float* ptsT = (float*)d_ws;                            // 4,194,304 f
  float* sqx  = ptsT + (size_t)NB*NN*NCF;                // 65,536 f
  int*   fidx = (int*)(sqx + (size_t)NB*NN);             // 16,384 i
  float* dcen = (float*)(fidx + NB*NS);                  // 16,384 f
  int*   kidx = (int*)(dcen + NB*NS);                    // 524,288 i
  unsigned short* z1 = (unsigned short*)(kidx + NPTS);   // 33,554,432 us
  unsigned short* z2 = z1 + (size_t)NPTS*64;             // 33,554,432 us
  float* m3   = (float*)(z2 + (size_t)NPTS*64);          // 2,097,152 f
  float* p1   = m3 + (size_t)NB*NS*128;                  // 4096*128 f
  float* p2   = p1 + 4096*128;                           // 4096*128 f
  float* p3   = p2 + 4096*128;                           // 4096*256 f
  float* bnp  = p3 + 4096*256;                           // 512 f (scale/shift x3)
  float* dstat= bnp + 512;                               // 2 f

  hipLaunchKernelGGL(prep_kernel,  dim3(256),  dim3(256), 0, stream, points, xyz, ptsT, sqx);
  hipLaunchKernelGGL(fps_kernel,   dim3(NB),   dim3(FT),  0, stream, xyz, fidx, newxyz);
  hipLaunchKernelGGL(dcen_kernel,  dim3(64),   dim3(256), 0, stream, density, fidx, dcen);
  hipLaunchKernelGGL(dstats_kernel,dim3(1),    dim3(256), 0, stream, dcen, dstat);
  hipLaunchKernelGGL(knn_kernel,   dim3(4096), dim3(256), 0, stream, xyz, sqx, newxyz, kidx);
  hipLaunchKernelGGL(conv1_kernel, dim3(4096), dim3(256), 0, stream, xyz, ptsT, newxyz, kidx, w0, b0, z1, p1);
  hipLaunchKernelGGL(mkbn_kernel,  dim3(64),   dim3(256), 0, stream, p1, 4096, 128, g0, be0, bnp+0,   bnp+64,  1.0f/(float)NPTS);
  hipLaunchKernelGGL(conv2_kernel, dim3(4096), dim3(256), 0, stream, z1, w1, b1, bnp+0, bnp+64, z2, p2);
  hipLaunchKernelGGL(mkbn_kernel,  dim3(64),   dim3(256), 0, stream, p2, 4096, 128, g1, be1, bnp+128, bnp+192, 1.0f/(float)NPTS);
  hipLaunchKernelGGL(conv3_kernel, dim3(4096), dim3(256), 0, stream, z2, w2, b2, bnp+128, bnp+192, m3, p3);
  hipLaunchKernelGGL(mkbn_kernel,  dim3(128),  dim3(256), 0, stream, p3, 4096, 256, g2, be2, bnp+256, bnp+384, 1.0f/(float)NPTS);
  hipLaunchKernelGGL(final_kernel, dim3(8192), dim3(256), 0, stream, m3, dcen, bnp+256, bnp+384, wd, bd, gd, bed, dstat, out1);
}